// Round 1
// baseline (6313.817 us; speedup 1.0000x reference)
//
#include <hip/hip_runtime.h>
#include <math.h>

typedef unsigned short u16;
typedef unsigned int u32;

#define B_ 2
#define T_ 4096
#define DM 512
#define NH 8
#define DH 64
#define DFF 2048
#define MTOT (B_*T_)   // 8192

using f32x4  = __attribute__((ext_vector_type(4))) float;
using bf16x8 = __attribute__((ext_vector_type(8))) short;

__device__ __forceinline__ float b2f(u16 u) {
  union { u32 u; float f; } v; v.u = ((u32)u) << 16; return v.f;
}
__device__ __forceinline__ u16 f2b(float f) {
  union { float f; u32 u; } v; v.f = f;
  u32 r = v.u + 0x7FFFu + ((v.u >> 16) & 1u);
  return (u16)(r >> 16);
}

// ---------------- embed: x = x_in*inp_w + inp_b + pos ----------------
__global__ __launch_bounds__(256) void embed_k(
    const float* __restrict__ x_in, const float* __restrict__ w,
    const float* __restrict__ bias, const float* __restrict__ pos,
    float* __restrict__ x) {
  int idx = blockIdx.x * 256 + threadIdx.x;      // over MTOT*DM
  int row = idx >> 9, d = idx & 511;
  int t = row & (T_ - 1);
  x[idx] = x_in[row] * w[d] + bias[d] + pos[t * DM + d];
}

// ---------------- layernorm fp32 -> bf16, one wave per row ----------------
__global__ __launch_bounds__(256) void ln_k(
    const float* __restrict__ x, const float* __restrict__ g,
    const float* __restrict__ bet, u16* __restrict__ y) {
  int wid = threadIdx.x >> 6, lane = threadIdx.x & 63;
  int row = blockIdx.x * 4 + wid;
  const float* xr = x + (size_t)row * DM + lane * 8;
  float4 a0 = *(const float4*)xr;
  float4 a1 = *(const float4*)(xr + 4);
  float v[8] = {a0.x, a0.y, a0.z, a0.w, a1.x, a1.y, a1.z, a1.w};
  float s = 0.f;
#pragma unroll
  for (int j = 0; j < 8; j++) s += v[j];
#pragma unroll
  for (int off = 32; off; off >>= 1) s += __shfl_xor(s, off);
  float mu = s * (1.0f / DM);
  float q = 0.f;
#pragma unroll
  for (int j = 0; j < 8; j++) { float e = v[j] - mu; q += e * e; }
#pragma unroll
  for (int off = 32; off; off >>= 1) q += __shfl_xor(q, off);
  float rs = rsqrtf(q * (1.0f / DM) + 1e-5f);
  float4 g0 = *(const float4*)(g + lane * 8);
  float4 g1 = *(const float4*)(g + lane * 8 + 4);
  float4 p0 = *(const float4*)(bet + lane * 8);
  float4 p1 = *(const float4*)(bet + lane * 8 + 4);
  float gg[8] = {g0.x, g0.y, g0.z, g0.w, g1.x, g1.y, g1.z, g1.w};
  float pp[8] = {p0.x, p0.y, p0.z, p0.w, p1.x, p1.y, p1.z, p1.w};
  u32 o[4];
#pragma unroll
  for (int j = 0; j < 4; j++) {
    float r0 = (v[2*j]   - mu) * rs * gg[2*j]   + pp[2*j];
    float r1 = (v[2*j+1] - mu) * rs * gg[2*j+1] + pp[2*j+1];
    o[j] = (u32)f2b(r0) | ((u32)f2b(r1) << 16);
  }
  uint4 st; st.x = o[0]; st.y = o[1]; st.z = o[2]; st.w = o[3];
  *(uint4*)(y + (size_t)row * DM + lane * 8) = st;
}

// ---------------- bf16 MFMA GEMM: C[M,N] = A[M,K](bf16) @ B[K,N](fp32 conv bf16)
// EPI: 0 = store bf16, 1 = Cf += acc (fp32 residual), 2 = gelu -> bf16
template<int EPI>
__global__ __launch_bounds__(256) void gemm_k(
    const u16* __restrict__ A, const float* __restrict__ Bw,
    u16* __restrict__ Cb, float* __restrict__ Cf,
    int M, int N, int K) {
  __shared__ u16 As[128][32];
  __shared__ u16 Bs[128][32];   // Bs[n][k]
  int tid = threadIdx.x;
  int lane = tid & 63, wid = tid >> 6;
  int wr = wid >> 1, wc = wid & 1;
  int m0 = blockIdx.y * 128, n0 = blockIdx.x * 128;
  f32x4 acc[4][4] = {};
  int arow = tid >> 1, akh = (tid & 1) * 16;
  int bk = tid >> 3, bn = (tid & 7) * 16;
  for (int k0 = 0; k0 < K; k0 += 32) {
    // stage A (already bf16): 128 x 32
    const uint4* pa = (const uint4*)(A + (size_t)(m0 + arow) * K + k0 + akh);
    *(uint4*)&As[arow][akh]     = pa[0];
    *(uint4*)&As[arow][akh + 8] = pa[1];
    // stage B (fp32 -> bf16, transposed into Bs[n][k])
    const float* pb = Bw + (size_t)(k0 + bk) * N + n0 + bn;
#pragma unroll
    for (int i = 0; i < 16; i += 4) {
      float4 f = *(const float4*)(pb + i);
      Bs[bn + i + 0][bk] = f2b(f.x);
      Bs[bn + i + 1][bk] = f2b(f.y);
      Bs[bn + i + 2][bk] = f2b(f.z);
      Bs[bn + i + 3][bk] = f2b(f.w);
    }
    __syncthreads();
    bf16x8 af[4], bfr[4];
    int r = lane & 15, kc = (lane >> 4) * 8;
#pragma unroll
    for (int m = 0; m < 4; m++) af[m]  = *(const bf16x8*)&As[wr*64 + m*16 + r][kc];
#pragma unroll
    for (int n = 0; n < 4; n++) bfr[n] = *(const bf16x8*)&Bs[wc*64 + n*16 + r][kc];
#pragma unroll
    for (int m = 0; m < 4; m++)
#pragma unroll
      for (int n = 0; n < 4; n++)
        acc[m][n] = __builtin_amdgcn_mfma_f32_16x16x32_bf16(af[m], bfr[n], acc[m][n], 0, 0, 0);
    __syncthreads();
  }
  int r4 = (lane >> 4) * 4, cN = lane & 15;
#pragma unroll
  for (int m = 0; m < 4; m++) {
#pragma unroll
    for (int n = 0; n < 4; n++) {
#pragma unroll
      for (int i = 0; i < 4; i++) {
        int row = m0 + wr*64 + m*16 + r4 + i;
        int col = n0 + wc*64 + n*16 + cN;
        size_t off = (size_t)row * N + col;
        float v = acc[m][n][i];
        if (EPI == 0) {
          Cb[off] = f2b(v);
        } else if (EPI == 1) {
          Cf[off] += v;
        } else {
          float gl = 0.5f * v * (1.0f + erff(v * 0.70710678118654752f));
          Cb[off] = f2b(gl);
        }
      }
    }
  }
}

// ---------------- causal flash attention (fp32 math, bf16 I/O) ----------------
// grid (T/64, B*NH), block 256. 64 q-rows per block, K/V tiles of 64.
__global__ __launch_bounds__(256) void attn_k(const u16* __restrict__ qkv,
                                              u16* __restrict__ outp) {
  __shared__ float Qs[64][76];
  __shared__ float Ks[64][76];
  __shared__ float Vs[64][76];
  __shared__ float Ps[64][76];   // transposed: Ps[k][q]
  __shared__ float mrow[64], lrow[64], srow[64];
  int tid = threadIdx.x;
  int qb = blockIdx.x, bh = blockIdx.y;
  int b = bh >> 3, h = bh & 7;
  int q0 = qb * 64;
  size_t base = (size_t)b * T_ * (3 * DM);
  int sr = tid >> 2, sc = (tid & 3) * 16;
  {
    const u16* pq = qkv + base + (size_t)(q0 + sr) * (3 * DM) + h * DH + sc;
#pragma unroll
    for (int ii = 0; ii < 4; ii++) {
      float4 f;
      f.x = b2f(pq[4*ii+0]) * 0.125f;
      f.y = b2f(pq[4*ii+1]) * 0.125f;
      f.z = b2f(pq[4*ii+2]) * 0.125f;
      f.w = b2f(pq[4*ii+3]) * 0.125f;
      *(float4*)&Qs[sr][sc + 4*ii] = f;
    }
  }
  if (tid < 64) { mrow[tid] = -1e30f; lrow[tid] = 0.f; }
  float o[4][4] = {};
  int tr = tid >> 4, tc = tid & 15;
  for (int kt = 0; kt <= qb; kt++) {
    __syncthreads();   // prev PV done; Q staged (first iter)
    {
      const u16* pk = qkv + base + (size_t)(kt*64 + sr) * (3*DM) + DM + h*DH + sc;
      const u16* pv = pk + DM;
#pragma unroll
      for (int ii = 0; ii < 4; ii++) {
        float4 f;
        f.x = b2f(pk[4*ii+0]); f.y = b2f(pk[4*ii+1]);
        f.z = b2f(pk[4*ii+2]); f.w = b2f(pk[4*ii+3]);
        *(float4*)&Ks[sr][sc + 4*ii] = f;
        float4 g;
        g.x = b2f(pv[4*ii+0]); g.y = b2f(pv[4*ii+1]);
        g.z = b2f(pv[4*ii+2]); g.w = b2f(pv[4*ii+3]);
        *(float4*)&Vs[sr][sc + 4*ii] = g;
      }
    }
    __syncthreads();   // K,V ready
    float sacc[4][4] = {};
    for (int d = 0; d < 64; d += 4) {
      float4 qv[4], kv[4];
#pragma unroll
      for (int i = 0; i < 4; i++) qv[i] = *(const float4*)&Qs[tr*4+i][d];
#pragma unroll
      for (int j = 0; j < 4; j++) kv[j] = *(const float4*)&Ks[tc*4+j][d];
#pragma unroll
      for (int i = 0; i < 4; i++)
#pragma unroll
        for (int j = 0; j < 4; j++)
          sacc[i][j] += qv[i].x*kv[j].x + qv[i].y*kv[j].y
                      + qv[i].z*kv[j].z + qv[i].w*kv[j].w;
    }
    if (kt == qb) {
#pragma unroll
      for (int i = 0; i < 4; i++)
#pragma unroll
        for (int j = 0; j < 4; j++)
          if (tc*4+j > tr*4+i) sacc[i][j] = -1e30f;
    }
#pragma unroll
    for (int i = 0; i < 4; i++)
#pragma unroll
      for (int j = 0; j < 4; j++)
        Ps[tc*4+j][tr*4+i] = sacc[i][j];
    __syncthreads();   // S ready
    if (tid < 64) {
      int q = tid;
      float mold = mrow[q];
      float mx = mold;
      for (int k = 0; k < 64; k++) mx = fmaxf(mx, Ps[k][q]);
      float corr = __expf(mold - mx);
      float sum = 0.f;
      for (int k = 0; k < 64; k++) {
        float p = __expf(Ps[k][q] - mx);
        Ps[k][q] = p;
        sum += p;
      }
      lrow[q] = lrow[q] * corr + sum;
      mrow[q] = mx;
      srow[q] = corr;
    }
    __syncthreads();   // P ready
    float cs[4];
#pragma unroll
    for (int i = 0; i < 4; i++) cs[i] = srow[tr*4+i];
#pragma unroll
    for (int i = 0; i < 4; i++)
#pragma unroll
      for (int j = 0; j < 4; j++) o[i][j] *= cs[i];
    for (int k = 0; k < 64; k++) {
      float4 vv = *(const float4*)&Vs[k][tc*4];
      float4 pq = *(const float4*)&Ps[k][tr*4];
      float pr[4] = {pq.x, pq.y, pq.z, pq.w};
#pragma unroll
      for (int i = 0; i < 4; i++) {
        o[i][0] += pr[i] * vv.x;
        o[i][1] += pr[i] * vv.y;
        o[i][2] += pr[i] * vv.z;
        o[i][3] += pr[i] * vv.w;
      }
    }
  }
  float inv[4];
#pragma unroll
  for (int i = 0; i < 4; i++) inv[i] = 1.0f / lrow[tr*4+i];
#pragma unroll
  for (int i = 0; i < 4; i++) {
    int row = q0 + tr*4 + i;
    u16* po = outp + ((size_t)b * T_ + row) * DM + h * DH + tc * 4;
#pragma unroll
    for (int j = 0; j < 4; j++) po[j] = f2b(o[i][j] * inv[i]);
  }
}

// ---------------- head: out = lnf(bf16) @ head_w + head_b, N=64 ----------------
__global__ __launch_bounds__(256) void head_k(
    const u16* __restrict__ xb, const float* __restrict__ W,
    const float* __restrict__ bias, float* __restrict__ out) {
  int wid = threadIdx.x >> 6, lane = threadIdx.x & 63;
  int row = blockIdx.x * 4 + wid;
  const u16* xr = xb + (size_t)row * DM;
  float acc = 0.f;
  for (int d = 0; d < DM; d++) acc += b2f(xr[d]) * W[d * 64 + lane];
  out[(size_t)row * 64 + lane] = acc + bias[lane];
}

extern "C" void kernel_launch(void* const* d_in, const int* in_sizes, int n_in,
                              void* d_out, int out_size, void* d_ws, size_t ws_size,
                              hipStream_t stream) {
  (void)in_sizes; (void)n_in; (void)out_size; (void)ws_size;
  const float* x_in  = (const float*)d_in[0];
  const float* inp_w = (const float*)d_in[1];
  const float* inp_b = (const float*)d_in[2];
  const float* pos   = (const float*)d_in[3];
  const float* ln1g  = (const float*)d_in[4];
  const float* ln1b  = (const float*)d_in[5];
  const float* qkvw  = (const float*)d_in[6];
  const float* projw = (const float*)d_in[7];
  const float* ln2g  = (const float*)d_in[8];
  const float* ln2b  = (const float*)d_in[9];
  const float* fc1w  = (const float*)d_in[10];
  const float* fc2w  = (const float*)d_in[11];
  const float* lnfg  = (const float*)d_in[12];
  const float* lnfb  = (const float*)d_in[13];
  const float* headw = (const float*)d_in[14];
  const float* headb = (const float*)d_in[15];

  char* ws = (char*)d_ws;
  float* x    = (float*)ws;                              // MTOT*DM fp32   (16.8 MB)
  u16*  lnb   = (u16*)(ws + (size_t)MTOT*DM*4);          // MTOT*DM bf16   ( 8.4 MB)
  char* r3    = ws + (size_t)MTOT*DM*4 + (size_t)MTOT*DM*2;
  u16*  qkv   = (u16*)r3;                                // MTOT*1536 bf16 (25.2 MB)
  u16*  attno = (u16*)(r3 + (size_t)MTOT*3*DM*2);        // MTOT*DM bf16   ( 8.4 MB)
  u16*  ff    = (u16*)r3;                                // MTOT*DFF bf16  (reuses qkv+attno)

  embed_k<<<(MTOT*DM)/256, 256, 0, stream>>>(x_in, inp_w, inp_b, pos, x);
  for (int l = 0; l < 4; l++) {
    ln_k<<<MTOT/4, 256, 0, stream>>>(x, ln1g + l*DM, ln1b + l*DM, lnb);
    gemm_k<0><<<dim3(12, 64), 256, 0, stream>>>(lnb, qkvw + (size_t)l*DM*3*DM,
                                                qkv, nullptr, MTOT, 3*DM, DM);
    attn_k<<<dim3(T_/64, B_*NH), 256, 0, stream>>>(qkv, attno);
    gemm_k<1><<<dim3(4, 64), 256, 0, stream>>>(attno, projw + (size_t)l*DM*DM,
                                               nullptr, x, MTOT, DM, DM);
    ln_k<<<MTOT/4, 256, 0, stream>>>(x, ln2g + l*DM, ln2b + l*DM, lnb);
    gemm_k<2><<<dim3(16, 64), 256, 0, stream>>>(lnb, fc1w + (size_t)l*DM*DFF,
                                                ff, nullptr, MTOT, DFF, DM);
    gemm_k<1><<<dim3(4, 64), 256, 0, stream>>>(ff, fc2w + (size_t)l*DFF*DM,
                                               nullptr, x, MTOT, DM, DFF);
  }
  ln_k<<<MTOT/4, 256, 0, stream>>>(x, lnfg, lnfb, lnb);
  head_k<<<MTOT/4, 256, 0, stream>>>(lnb, headw, headb, (float*)d_out);
}

// Round 2
// 1334.860 us; speedup vs baseline: 4.7299x; 4.7299x over previous
//
#include <hip/hip_runtime.h>
#include <math.h>

typedef unsigned short u16;
typedef unsigned int u32;

#define B_ 2
#define T_ 4096
#define DM 512
#define NH 8
#define DH 64
#define DFF 2048
#define MTOT (B_*T_)   // 8192

using f32x4  = __attribute__((ext_vector_type(4))) float;
using f32x16 = __attribute__((ext_vector_type(16))) float;
using bf16x8 = __attribute__((ext_vector_type(8))) short;

__device__ __forceinline__ float b2f(u16 u) {
  union { u32 u; float f; } v; v.u = ((u32)u) << 16; return v.f;
}
__device__ __forceinline__ u16 f2b(float f) {
  union { float f; u32 u; } v; v.f = f;
  u32 r = v.u + 0x7FFFu + ((v.u >> 16) & 1u);
  return (u16)(r >> 16);
}
__device__ __forceinline__ u32 pk2(float a, float b) {
  return (u32)f2b(a) | ((u32)f2b(b) << 16);
}

// LDS swizzle for [64][64] u16 tiles, row stride 64 (128B).
// slot(row,col) spreads banks evenly for row-parallel b128 reads and all
// staging write patterns. Returns u16 element offset.
__device__ __forceinline__ int lsw(int row, int col) {
  int slot = ((col >> 3) + (row >> 3) + 2 * (row & 7)) & 7;
  return (row << 6) + (slot << 3) + (col & 7);
}

// ---------------- embed ----------------
__global__ __launch_bounds__(256) void embed_k(
    const float* __restrict__ x_in, const float* __restrict__ w,
    const float* __restrict__ bias, const float* __restrict__ pos,
    float* __restrict__ x) {
  int idx = blockIdx.x * 256 + threadIdx.x;
  int row = idx >> 9, d = idx & 511;
  int t = row & (T_ - 1);
  x[idx] = x_in[row] * w[d] + bias[d] + pos[t * DM + d];
}

// ---------------- layernorm fp32 -> bf16 ----------------
__global__ __launch_bounds__(256) void ln_k(
    const float* __restrict__ x, const float* __restrict__ g,
    const float* __restrict__ bet, u16* __restrict__ y) {
  int wid = threadIdx.x >> 6, lane = threadIdx.x & 63;
  int row = blockIdx.x * 4 + wid;
  const float* xr = x + (size_t)row * DM + lane * 8;
  float4 a0 = *(const float4*)xr;
  float4 a1 = *(const float4*)(xr + 4);
  float v[8] = {a0.x, a0.y, a0.z, a0.w, a1.x, a1.y, a1.z, a1.w};
  float s = 0.f;
#pragma unroll
  for (int j = 0; j < 8; j++) s += v[j];
#pragma unroll
  for (int off = 32; off; off >>= 1) s += __shfl_xor(s, off);
  float mu = s * (1.0f / DM);
  float q = 0.f;
#pragma unroll
  for (int j = 0; j < 8; j++) { float e = v[j] - mu; q += e * e; }
#pragma unroll
  for (int off = 32; off; off >>= 1) q += __shfl_xor(q, off);
  float rs = rsqrtf(q * (1.0f / DM) + 1e-5f);
  float4 g0 = *(const float4*)(g + lane * 8);
  float4 g1 = *(const float4*)(g + lane * 8 + 4);
  float4 p0 = *(const float4*)(bet + lane * 8);
  float4 p1 = *(const float4*)(bet + lane * 8 + 4);
  float gg[8] = {g0.x, g0.y, g0.z, g0.w, g1.x, g1.y, g1.z, g1.w};
  float pp[8] = {p0.x, p0.y, p0.z, p0.w, p1.x, p1.y, p1.z, p1.w};
  u32 o[4];
#pragma unroll
  for (int j = 0; j < 4; j++) {
    float r0 = (v[2*j]   - mu) * rs * gg[2*j]   + pp[2*j];
    float r1 = (v[2*j+1] - mu) * rs * gg[2*j+1] + pp[2*j+1];
    o[j] = pk2(r0, r1);
  }
  uint4 st; st.x = o[0]; st.y = o[1]; st.z = o[2]; st.w = o[3];
  *(uint4*)(y + (size_t)row * DM + lane * 8) = st;
}

// ---------------- weight convert+transpose: W[K][N] fp32 -> Wt[N][K] bf16 ----
__global__ __launch_bounds__(256) void wconv_k(
    const float* __restrict__ W, u16* __restrict__ Wt, int K, int N) {
  __shared__ float tile[32][33];
  const float* Wl = W + (size_t)blockIdx.z * K * N;
  u16* Wtl = Wt + (size_t)blockIdx.z * K * N;
  int k0 = blockIdx.x * 32, n0 = blockIdx.y * 32;
  int r = threadIdx.x >> 3, c4 = (threadIdx.x & 7) * 4;
  *(float4*)&tile[r][c4] = *(const float4*)(Wl + (size_t)(k0 + r) * N + n0 + c4);
  __syncthreads();
  ushort4 st;
  st.x = f2b(tile[c4 + 0][r]);
  st.y = f2b(tile[c4 + 1][r]);
  st.z = f2b(tile[c4 + 2][r]);
  st.w = f2b(tile[c4 + 3][r]);
  *(ushort4*)(Wtl + (size_t)(n0 + r) * K + k0 + c4) = st;
}

// ---------------- bf16 MFMA GEMM: C[M,N] = A[M,K] @ Bt[N,K]^T ----------------
// EPI: 0 = store bf16 (cols < scale_cols get *0.125), 1 = Cf += acc, 2 = gelu->bf16
template<int EPI>
__global__ __launch_bounds__(256) void gemm_k(
    const u16* __restrict__ A, const u16* __restrict__ Bt,
    u16* __restrict__ Cb, float* __restrict__ Cf,
    int M, int N, int K, int scale_cols) {
  __shared__ u16 As[128][32];
  __shared__ u16 Bs[128][32];   // Bs[n][k]
  int tid = threadIdx.x;
  int lane = tid & 63, wid = tid >> 6;
  int wr = wid >> 1, wc = wid & 1;
  int m0 = blockIdx.y * 128, n0 = blockIdx.x * 128;
  f32x4 acc[4][4] = {};
  int arow = tid >> 1, akh = (tid & 1) * 16;
  for (int k0 = 0; k0 < K; k0 += 32) {
    const uint4* pa = (const uint4*)(A + (size_t)(m0 + arow) * K + k0 + akh);
    *(uint4*)&As[arow][akh]     = pa[0];
    *(uint4*)&As[arow][akh + 8] = pa[1];
    const uint4* pb = (const uint4*)(Bt + (size_t)(n0 + arow) * K + k0 + akh);
    *(uint4*)&Bs[arow][akh]     = pb[0];
    *(uint4*)&Bs[arow][akh + 8] = pb[1];
    __syncthreads();
    bf16x8 af[4], bfr[4];
    int r = lane & 15, kc = (lane >> 4) * 8;
#pragma unroll
    for (int m = 0; m < 4; m++) af[m]  = *(const bf16x8*)&As[wr*64 + m*16 + r][kc];
#pragma unroll
    for (int n = 0; n < 4; n++) bfr[n] = *(const bf16x8*)&Bs[wc*64 + n*16 + r][kc];
#pragma unroll
    for (int m = 0; m < 4; m++)
#pragma unroll
      for (int n = 0; n < 4; n++)
        acc[m][n] = __builtin_amdgcn_mfma_f32_16x16x32_bf16(af[m], bfr[n], acc[m][n], 0, 0, 0);
    __syncthreads();
  }
  int r4 = (lane >> 4) * 4, cN = lane & 15;
#pragma unroll
  for (int m = 0; m < 4; m++) {
#pragma unroll
    for (int n = 0; n < 4; n++) {
      int col = n0 + wc*64 + n*16 + cN;
#pragma unroll
      for (int i = 0; i < 4; i++) {
        int row = m0 + wr*64 + m*16 + r4 + i;
        size_t off = (size_t)row * N + col;
        float v = acc[m][n][i];
        if (EPI == 0) {
          if (col < scale_cols) v *= 0.125f;
          Cb[off] = f2b(v);
        } else if (EPI == 1) {
          Cf[off] += v;
        } else {
          float gl = 0.5f * v * (1.0f + erff(v * 0.70710678118654752f));
          Cb[off] = f2b(gl);
        }
      }
    }
  }
}

// ---------------- MFMA causal flash attention ----------------
// grid (T/128, B*NH), block 256 = 4 waves; wave w owns q rows q0+32w..+31.
// Swapped QK^T: S^T = K.Q^T so softmax state is lane-local (q = lane&31).
__global__ __launch_bounds__(256) void attn_k(const u16* __restrict__ qkv,
                                              u16* __restrict__ outp) {
  __shared__ u16 Ks[64 * 64];
  __shared__ u16 Vt[64 * 64];
  int tid = threadIdx.x;
  int w = tid >> 6, l = tid & 63;
  int hh = l >> 5, c = l & 31;
  int qb = blockIdx.x, bh = blockIdx.y;
  int b = bh >> 3, hd = bh & 7;
  int q0w = qb * 128 + w * 32;
  int q_abs = q0w + c;
  size_t base = (size_t)b * T_ * 1536;
  // Q fragments (B-operand): lane holds q-col = c, d-chunk hh*8, already *0.125
  bf16x8 qf[4];
  const u16* qp = qkv + base + (size_t)q_abs * 1536 + hd * 64 + hh * 8;
#pragma unroll
  for (int kk = 0; kk < 4; kk++) qf[kk] = *(const bf16x8*)(qp + kk * 16);
  f32x16 oa0 = {}, oa1 = {};
  float m_run = -1e30f, l_run = 0.f;
  int tkr = tid >> 3, td8 = tid & 7;
  int nt = 2 * qb + 2;
  for (int kt = 0; kt < nt; kt++) {
    __syncthreads();
    // stage K (row-major, swizzled) and V^T (transposed, swizzled)
#pragma unroll
    for (int rr = 0; rr < 2; rr++) {
      int r = tkr + rr * 32;
      const u16* srcb = qkv + base + (size_t)(kt * 64 + r) * 1536 + DM + hd * 64 + td8 * 8;
      uint4 k4 = *(const uint4*)srcb;
      uint4 v4 = *(const uint4*)(srcb + DM);
      *(uint4*)&Ks[lsw(r, td8 * 8)] = k4;
      const u16* vv = (const u16*)&v4;
#pragma unroll
      for (int j = 0; j < 8; j++) Vt[lsw(td8 * 8 + j, r)] = vv[j];
    }
    __syncthreads();
    if (kt * 64 > q0w + 31) continue;          // fully masked for this wave
    bool needMask = (kt * 64 + 63 > q0w);
    // S^T = K . Q^T   (two 32-row k-tiles)
    f32x16 sa0 = {}, sa1 = {};
#pragma unroll
    for (int kk = 0; kk < 4; kk++) {
      bf16x8 ka = *(const bf16x8*)&Ks[lsw(c,      kk * 16 + hh * 8)];
      bf16x8 kb = *(const bf16x8*)&Ks[lsw(32 + c, kk * 16 + hh * 8)];
      sa0 = __builtin_amdgcn_mfma_f32_32x32x16_bf16(ka, qf[kk], sa0, 0, 0, 0);
      sa1 = __builtin_amdgcn_mfma_f32_32x32x16_bf16(kb, qf[kk], sa1, 0, 0, 0);
    }
    if (needMask) {
#pragma unroll
      for (int g = 0; g < 4; g++)
#pragma unroll
        for (int i = 0; i < 4; i++) {
          int krow = kt * 64 + g * 8 + hh * 4 + i;
          if (krow > q_abs)      sa0[g * 4 + i] = -1e30f;
          if (krow + 32 > q_abs) sa1[g * 4 + i] = -1e30f;
        }
    }
    // online softmax (lane-local rows; halves merged via shfl_xor 32)
    float pm = -1e30f;
#pragma unroll
    for (int r = 0; r < 16; r++) { pm = fmaxf(pm, sa0[r]); pm = fmaxf(pm, sa1[r]); }
    pm = fmaxf(pm, __shfl_xor(pm, 32));
    float mnew = fmaxf(m_run, pm);
    float corr = __expf(m_run - mnew);
    m_run = mnew;
    float lsum = 0.f;
#pragma unroll
    for (int r = 0; r < 16; r++) {
      float e0 = __expf(sa0[r] - mnew); sa0[r] = e0; lsum += e0;
      float e1 = __expf(sa1[r] - mnew); sa1[r] = e1; lsum += e1;
    }
    lsum += __shfl_xor(lsum, 32);
    l_run = l_run * corr + lsum;
#pragma unroll
    for (int r = 0; r < 16; r++) { oa0[r] *= corr; oa1[r] *= corr; }
    // pack P^T into PV B-fragments via bf16 pairs + half-swap
    u32 Aw[8], Bw_[8], Asw[8], Bsw[8];   // index = m*4 + r2
#pragma unroll
    for (int r2 = 0; r2 < 4; r2++) {
      Aw[r2]      = pk2(sa0[4 * r2 + 0], sa0[4 * r2 + 1]);
      Bw_[r2]     = pk2(sa0[4 * r2 + 2], sa0[4 * r2 + 3]);
      Aw[4 + r2]  = pk2(sa1[4 * r2 + 0], sa1[4 * r2 + 1]);
      Bw_[4 + r2] = pk2(sa1[4 * r2 + 2], sa1[4 * r2 + 3]);
    }
#pragma unroll
    for (int i = 0; i < 8; i++) {
      Asw[i] = __shfl_xor(Aw[i], 32);
      Bsw[i] = __shfl_xor(Bw_[i], 32);
    }
    // O^T += V^T . P^T
#pragma unroll
    for (int ks = 0; ks < 4; ks++) {
      int mo = (ks >> 1) * 4;
      int r2e = mo + 2 * (ks & 1), r2o = r2e + 1;
      union { u32 wd[4]; bf16x8 v; } u;
      u.wd[0] = hh ? Asw[r2o] : Aw[r2e];
      u.wd[1] = hh ? Bsw[r2o] : Bw_[r2e];
      u.wd[2] = hh ? Aw[r2o]  : Asw[r2e];
      u.wd[3] = hh ? Bw_[r2o] : Bsw[r2e];
      bf16x8 va = *(const bf16x8*)&Vt[lsw(c,      ks * 16 + hh * 8)];
      bf16x8 vb = *(const bf16x8*)&Vt[lsw(32 + c, ks * 16 + hh * 8)];
      oa0 = __builtin_amdgcn_mfma_f32_32x32x16_bf16(va, u.v, oa0, 0, 0, 0);
      oa1 = __builtin_amdgcn_mfma_f32_32x32x16_bf16(vb, u.v, oa1, 0, 0, 0);
    }
  }
  float invl = 1.0f / l_run;
  u16* orow = outp + ((size_t)b * T_ + q_abs) * DM + hd * 64;
#pragma unroll
  for (int g = 0; g < 4; g++) {
    ushort4 s0, s1;
    s0.x = f2b(oa0[4*g+0] * invl); s0.y = f2b(oa0[4*g+1] * invl);
    s0.z = f2b(oa0[4*g+2] * invl); s0.w = f2b(oa0[4*g+3] * invl);
    s1.x = f2b(oa1[4*g+0] * invl); s1.y = f2b(oa1[4*g+1] * invl);
    s1.z = f2b(oa1[4*g+2] * invl); s1.w = f2b(oa1[4*g+3] * invl);
    int d0 = g * 8 + hh * 4;
    *(ushort4*)(orow + d0)      = s0;
    *(ushort4*)(orow + 32 + d0) = s1;
  }
}

// ---------------- head ----------------
__global__ __launch_bounds__(256) void head_k(
    const u16* __restrict__ xb, const float* __restrict__ W,
    const float* __restrict__ bias, float* __restrict__ out) {
  int wid = threadIdx.x >> 6, lane = threadIdx.x & 63;
  int row = blockIdx.x * 4 + wid;
  const u16* xr = xb + (size_t)row * DM;
  float acc = 0.f;
  for (int d = 0; d < DM; d++) acc += b2f(xr[d]) * W[d * 64 + lane];
  out[(size_t)row * 64 + lane] = acc + bias[lane];
}

extern "C" void kernel_launch(void* const* d_in, const int* in_sizes, int n_in,
                              void* d_out, int out_size, void* d_ws, size_t ws_size,
                              hipStream_t stream) {
  (void)in_sizes; (void)n_in; (void)out_size; (void)ws_size;
  const float* x_in  = (const float*)d_in[0];
  const float* inp_w = (const float*)d_in[1];
  const float* inp_b = (const float*)d_in[2];
  const float* pos   = (const float*)d_in[3];
  const float* ln1g  = (const float*)d_in[4];
  const float* ln1b  = (const float*)d_in[5];
  const float* qkvw  = (const float*)d_in[6];
  const float* projw = (const float*)d_in[7];
  const float* ln2g  = (const float*)d_in[8];
  const float* ln2b  = (const float*)d_in[9];
  const float* fc1w  = (const float*)d_in[10];
  const float* fc2w  = (const float*)d_in[11];
  const float* lnfg  = (const float*)d_in[12];
  const float* lnfb  = (const float*)d_in[13];
  const float* headw = (const float*)d_in[14];
  const float* headb = (const float*)d_in[15];

  char* ws = (char*)d_ws;
  size_t off = 0;
  float* x    = (float*)(ws + off); off += (size_t)MTOT * DM * 4;
  u16*  lnb   = (u16*)(ws + off);   off += (size_t)MTOT * DM * 2;
  u16*  qkvb  = (u16*)(ws + off);   off += (size_t)MTOT * 3 * DM * 2;
  u16*  attno = (u16*)(ws + off);   off += (size_t)MTOT * DM * 2;
  u16*  ff    = qkvb;  // reuses qkv+attno regions (33.5 MB)
  u16*  qkvt  = (u16*)(ws + off);   off += (size_t)4 * DM * 3 * DM * 2;
  u16*  projt = (u16*)(ws + off);   off += (size_t)4 * DM * DM * 2;
  u16*  fc1t  = (u16*)(ws + off);   off += (size_t)4 * DM * DFF * 2;
  u16*  fc2t  = (u16*)(ws + off);   off += (size_t)4 * DFF * DM * 2;

  // one-time (per call) weight convert+transpose to bf16 [N][K]
  wconv_k<<<dim3(16, 48, 4), 256, 0, stream>>>(qkvw,  qkvt, DM, 3 * DM);
  wconv_k<<<dim3(16, 16, 4), 256, 0, stream>>>(projw, projt, DM, DM);
  wconv_k<<<dim3(16, 64, 4), 256, 0, stream>>>(fc1w,  fc1t, DM, DFF);
  wconv_k<<<dim3(64, 16, 4), 256, 0, stream>>>(fc2w,  fc2t, DFF, DM);

  embed_k<<<(MTOT * DM) / 256, 256, 0, stream>>>(x_in, inp_w, inp_b, pos, x);
  for (int ly = 0; ly < 4; ly++) {
    ln_k<<<MTOT / 4, 256, 0, stream>>>(x, ln1g + ly * DM, ln1b + ly * DM, lnb);
    gemm_k<0><<<dim3(12, 64), 256, 0, stream>>>(lnb, qkvt + (size_t)ly * DM * 3 * DM,
                                                qkvb, nullptr, MTOT, 3 * DM, DM, DM);
    attn_k<<<dim3(T_ / 128, B_ * NH), 256, 0, stream>>>(qkvb, attno);
    gemm_k<1><<<dim3(4, 64), 256, 0, stream>>>(attno, projt + (size_t)ly * DM * DM,
                                               nullptr, x, MTOT, DM, DM, 0);
    ln_k<<<MTOT / 4, 256, 0, stream>>>(x, ln2g + ly * DM, ln2b + ly * DM, lnb);
    gemm_k<2><<<dim3(16, 64), 256, 0, stream>>>(lnb, fc1t + (size_t)ly * DM * DFF,
                                                ff, nullptr, MTOT, DFF, DM, 0);
    gemm_k<1><<<dim3(4, 64), 256, 0, stream>>>(ff, fc2t + (size_t)ly * DFF * DM,
                                               nullptr, x, MTOT, DM, DFF, 0);
  }
  ln_k<<<MTOT / 4, 256, 0, stream>>>(x, lnfg, lnfb, lnb);
  head_k<<<MTOT / 4, 256, 0, stream>>>(lnb, headw, headb, (float*)d_out);
}

// Round 3
// 1188.466 us; speedup vs baseline: 5.3126x; 1.1232x over previous
//
#include <hip/hip_runtime.h>
#include <math.h>

typedef unsigned short u16;
typedef unsigned int u32;

#define B_ 2
#define T_ 4096
#define DM 512
#define NH 8
#define DH 64
#define DFF 2048
#define MTOT (B_*T_)   // 8192

// Q pre-scale: (1/sqrt(64)) * log2(e)  -> softmax runs in exp2 domain
#define SCALEQ 0.18033688011112042f

using f32x4  = __attribute__((ext_vector_type(4))) float;
using f32x16 = __attribute__((ext_vector_type(16))) float;
using bf16x8 = __attribute__((ext_vector_type(8))) short;

__device__ __forceinline__ float b2f(u16 u) {
  union { u32 u; float f; } v; v.u = ((u32)u) << 16; return v.f;
}
__device__ __forceinline__ u16 f2b(float f) {
  union { float f; u32 u; } v; v.f = f;
  u32 r = v.u + 0x7FFFu + ((v.u >> 16) & 1u);
  return (u16)(r >> 16);
}
// packed f32 pair -> bf16 pair (RTNE), single VALU op
__device__ __forceinline__ u32 cvtpk(float lo, float hi) {
  u32 r;
  asm("v_cvt_pk_bf16_f32 %0, %1, %2" : "=v"(r) : "v"(lo), "v"(hi));
  return r;
}
#if __has_builtin(__builtin_amdgcn_exp2f)
#define EXP2(x) __builtin_amdgcn_exp2f(x)
#else
#define EXP2(x) __expf((x) * 0.6931471805599453f)
#endif
#if __has_builtin(__builtin_amdgcn_rcpf)
#define RCP(x) __builtin_amdgcn_rcpf(x)
#else
#define RCP(x) (1.0f / (x))
#endif

// async global->LDS, 16B per lane, dest = uniform base + lane*16
__device__ __forceinline__ void gload_lds(const u16* g, u16* l) {
  __builtin_amdgcn_global_load_lds(
      (const __attribute__((address_space(1))) void*)g,
      (__attribute__((address_space(3))) void*)l, 16, 0, 0);
}

// LDS swizzle for [64][64] u16 tiles (128B rows). Returns u16 element offset.
__device__ __forceinline__ int lsw(int row, int col) {
  int slot = ((col >> 3) + (row >> 3) + 2 * (row & 7)) & 7;
  return (row << 6) + (slot << 3) + (col & 7);
}

// ---------------- embed ----------------
__global__ __launch_bounds__(256) void embed_k(
    const float* __restrict__ x_in, const float* __restrict__ w,
    const float* __restrict__ bias, const float* __restrict__ pos,
    float* __restrict__ x) {
  int idx = blockIdx.x * 256 + threadIdx.x;
  int row = idx >> 9, d = idx & 511;
  int t = row & (T_ - 1);
  x[idx] = x_in[row] * w[d] + bias[d] + pos[t * DM + d];
}

// ---------------- layernorm fp32 -> bf16 ----------------
__global__ __launch_bounds__(256) void ln_k(
    const float* __restrict__ x, const float* __restrict__ g,
    const float* __restrict__ bet, u16* __restrict__ y) {
  int wid = threadIdx.x >> 6, lane = threadIdx.x & 63;
  int row = blockIdx.x * 4 + wid;
  const float* xr = x + (size_t)row * DM + lane * 8;
  float4 a0 = *(const float4*)xr;
  float4 a1 = *(const float4*)(xr + 4);
  float v[8] = {a0.x, a0.y, a0.z, a0.w, a1.x, a1.y, a1.z, a1.w};
  float s = 0.f;
#pragma unroll
  for (int j = 0; j < 8; j++) s += v[j];
#pragma unroll
  for (int off = 32; off; off >>= 1) s += __shfl_xor(s, off);
  float mu = s * (1.0f / DM);
  float q = 0.f;
#pragma unroll
  for (int j = 0; j < 8; j++) { float e = v[j] - mu; q += e * e; }
#pragma unroll
  for (int off = 32; off; off >>= 1) q += __shfl_xor(q, off);
  float rs = rsqrtf(q * (1.0f / DM) + 1e-5f);
  float4 g0 = *(const float4*)(g + lane * 8);
  float4 g1 = *(const float4*)(g + lane * 8 + 4);
  float4 p0 = *(const float4*)(bet + lane * 8);
  float4 p1 = *(const float4*)(bet + lane * 8 + 4);
  float gg[8] = {g0.x, g0.y, g0.z, g0.w, g1.x, g1.y, g1.z, g1.w};
  float pp[8] = {p0.x, p0.y, p0.z, p0.w, p1.x, p1.y, p1.z, p1.w};
  uint4 st;
  st.x = cvtpk((v[0]-mu)*rs*gg[0]+pp[0], (v[1]-mu)*rs*gg[1]+pp[1]);
  st.y = cvtpk((v[2]-mu)*rs*gg[2]+pp[2], (v[3]-mu)*rs*gg[3]+pp[3]);
  st.z = cvtpk((v[4]-mu)*rs*gg[4]+pp[4], (v[5]-mu)*rs*gg[5]+pp[5]);
  st.w = cvtpk((v[6]-mu)*rs*gg[6]+pp[6], (v[7]-mu)*rs*gg[7]+pp[7]);
  *(uint4*)(y + (size_t)row * DM + lane * 8) = st;
}

// ---------------- weight convert+transpose: W[K][N] fp32 -> Wt[N][K] bf16 ----
__global__ __launch_bounds__(256) void wconv_k(
    const float* __restrict__ W, u16* __restrict__ Wt, int K, int N) {
  __shared__ float tile[32][33];
  const float* Wl = W + (size_t)blockIdx.z * K * N;
  u16* Wtl = Wt + (size_t)blockIdx.z * K * N;
  int k0 = blockIdx.x * 32, n0 = blockIdx.y * 32;
  int r = threadIdx.x >> 3, c4 = (threadIdx.x & 7) * 4;
  *(float4*)&tile[r][c4] = *(const float4*)(Wl + (size_t)(k0 + r) * N + n0 + c4);
  __syncthreads();
  uint2 st;
  st.x = cvtpk(tile[c4 + 0][r], tile[c4 + 1][r]);
  st.y = cvtpk(tile[c4 + 2][r], tile[c4 + 3][r]);
  *(uint2*)(Wtl + (size_t)(n0 + r) * K + k0 + c4) = st;
}

// ---------------- bf16 MFMA GEMM: C[M,N] = A[M,K] @ Bt[N,K]^T ----------------
// m97 structure: global_load_lds(16B) staging, 2 barriers per K-step.
// EPI: 0 = store bf16 (cols < scale_cols get *SCALEQ), 1 = Cf += acc, 2 = gelu->bf16
template<int EPI>
__global__ __launch_bounds__(256) void gemm_k(
    const u16* __restrict__ A, const u16* __restrict__ Bt,
    u16* __restrict__ Cb, float* __restrict__ Cf,
    int M, int N, int K, int scale_cols) {
  __shared__ u16 As[128][32];
  __shared__ u16 Bs[128][32];   // Bs[n][k]
  int tid = threadIdx.x;
  int lane = tid & 63, wid = tid >> 6;
  int wr = wid >> 1, wc = wid & 1;
  int m0 = blockIdx.y * 128, n0 = blockIdx.x * 128;
  f32x4 acc[4][4] = {};
  // global_load_lds staging: wave wid covers rows 32*wid..32*wid+31 of both tiles
  int rsub = lane >> 2, ksub = (lane & 3) * 8;
  const u16* Ab = A  + (size_t)(m0 + wid * 32 + rsub) * K + ksub;
  const u16* Bb = Bt + (size_t)(n0 + wid * 32 + rsub) * K + ksub;
  u16* lA0 = &As[wid * 32][0];
  u16* lA1 = &As[wid * 32 + 16][0];
  u16* lB0 = &Bs[wid * 32][0];
  u16* lB1 = &Bs[wid * 32 + 16][0];
  for (int k0 = 0; k0 < K; k0 += 32) {
    gload_lds(Ab + k0, lA0);
    gload_lds(Ab + (size_t)16 * K + k0, lA1);
    gload_lds(Bb + k0, lB0);
    gload_lds(Bb + (size_t)16 * K + k0, lB1);
    __syncthreads();
    bf16x8 af[4], bfr[4];
    int r = lane & 15, kc = (lane >> 4) * 8;
#pragma unroll
    for (int m = 0; m < 4; m++) af[m]  = *(const bf16x8*)&As[wr*64 + m*16 + r][kc];
#pragma unroll
    for (int n = 0; n < 4; n++) bfr[n] = *(const bf16x8*)&Bs[wc*64 + n*16 + r][kc];
#pragma unroll
    for (int m = 0; m < 4; m++)
#pragma unroll
      for (int n = 0; n < 4; n++)
        acc[m][n] = __builtin_amdgcn_mfma_f32_16x16x32_bf16(af[m], bfr[n], acc[m][n], 0, 0, 0);
    __syncthreads();
  }
  int r4 = (lane >> 4) * 4, cN = lane & 15;
#pragma unroll
  for (int m = 0; m < 4; m++) {
#pragma unroll
    for (int n = 0; n < 4; n++) {
      int col = n0 + wc*64 + n*16 + cN;
#pragma unroll
      for (int i = 0; i < 4; i++) {
        int row = m0 + wr*64 + m*16 + r4 + i;
        size_t off = (size_t)row * N + col;
        float v = acc[m][n][i];
        if (EPI == 0) {
          if (col < scale_cols) v *= SCALEQ;
          Cb[off] = f2b(v);
        } else if (EPI == 1) {
          Cf[off] += v;
        } else {
          // tanh-form GELU: gl = v * (1 - 1/(exp2(v*(a + b*v^2)) + 1))
          float e = EXP2(v * (2.3022082f + 0.10294324f * v * v));
          Cb[off] = f2b(v * (1.0f - RCP(e + 1.0f)));
        }
      }
    }
  }
}

// ---------------- MFMA causal flash attention ----------------
// grid (T/128, B*NH), block 256 = 4 waves; wave w owns q rows q0+32w..+31.
// Swapped QK^T (S^T = K.Q^T): softmax state lane-local. Double-buffered K/V,
// one barrier per tile, async-stage split (loads for kt+1 issued pre-barrier).
// Softmax in exp2 domain (Q pre-scaled by SCALEQ in qkv epilogue).
__global__ __launch_bounds__(256) void attn_k(const u16* __restrict__ qkv,
                                              u16* __restrict__ outp) {
  __shared__ u16 Ks[2][64 * 64];
  __shared__ u16 Vt[2][64 * 64];
  int tid = threadIdx.x;
  int w = tid >> 6, l = tid & 63;
  int hh = l >> 5, c = l & 31;
  int qb = (int)gridDim.x - 1 - (int)blockIdx.x;   // longest blocks first
  int bh = blockIdx.y;
  int b = bh >> 3, hd = bh & 7;
  int q0w = qb * 128 + w * 32;
  int q_abs = q0w + c;
  size_t base = (size_t)b * T_ * 1536;
  bf16x8 qf[4];
  const u16* qp = qkv + base + (size_t)q_abs * 1536 + hd * 64 + hh * 8;
#pragma unroll
  for (int kk = 0; kk < 4; kk++) qf[kk] = *(const bf16x8*)(qp + kk * 16);
  f32x16 oa0 = {}, oa1 = {};
  float m_run = -1e30f, l_run = 0.f;
  // staging: thread handles kv-row pair (2sp, 2sp+1), d-chunk d8..d8+7
  int sp = tid >> 3, d8 = (tid & 7) * 8;
  int r0 = sp * 2, r1 = r0 + 1;
  const u16* kvbase = qkv + base + DM + hd * 64 + d8;
  uint4 kreg0, kreg1, vreg0, vreg1;
#define AGLOAD(KT) { \
    const u16* s0_ = kvbase + (size_t)((KT) * 64 + r0) * 1536; \
    kreg0 = *(const uint4*)s0_; vreg0 = *(const uint4*)(s0_ + DM); \
    const u16* s1_ = s0_ + 1536; \
    kreg1 = *(const uint4*)s1_; vreg1 = *(const uint4*)(s1_ + DM); }
  int nt = 2 * qb + 2;
  AGLOAD(0);
  for (int kt = 0; kt < nt; kt++) {
    int cur = kt & 1;
    u16* Kb = Ks[cur];
    u16* Vb = Vt[cur];
    // ds_write staged regs (K row-major swizzled; V transposed, kv-pairs packed)
    *(uint4*)&Kb[lsw(r0, d8)] = kreg0;
    *(uint4*)&Kb[lsw(r1, d8)] = kreg1;
    {
      const u16* v0 = (const u16*)&vreg0;
      const u16* v1 = (const u16*)&vreg1;
#pragma unroll
      for (int j = 0; j < 8; j++) {
        u32 pw = (u32)v0[j] | ((u32)v1[j] << 16);
        *(u32*)&Vb[lsw(d8 + j, r0)] = pw;
      }
    }
    if (kt + 1 < nt) AGLOAD(kt + 1);   // HBM latency hides under barrier+compute
    __syncthreads();
    if (kt * 64 > q0w + 31) continue;  // fully masked for this wave
    bool needMask = (kt * 64 + 63 > q0w);
    f32x16 sa0 = {}, sa1 = {};
#pragma unroll
    for (int kk = 0; kk < 4; kk++) {
      bf16x8 ka  = *(const bf16x8*)&Kb[lsw(c,      kk * 16 + hh * 8)];
      bf16x8 kb2 = *(const bf16x8*)&Kb[lsw(32 + c, kk * 16 + hh * 8)];
      sa0 = __builtin_amdgcn_mfma_f32_32x32x16_bf16(ka,  qf[kk], sa0, 0, 0, 0);
      sa1 = __builtin_amdgcn_mfma_f32_32x32x16_bf16(kb2, qf[kk], sa1, 0, 0, 0);
    }
    if (needMask) {
#pragma unroll
      for (int g = 0; g < 4; g++)
#pragma unroll
        for (int i = 0; i < 4; i++) {
          int krow = kt * 64 + g * 8 + hh * 4 + i;
          if (krow > q_abs)      sa0[g * 4 + i] = -1e30f;
          if (krow + 32 > q_abs) sa1[g * 4 + i] = -1e30f;
        }
    }
    // online softmax with defer-max (THR=8), exp2 domain
    float pm = -1e30f;
#pragma unroll
    for (int r = 0; r < 16; r++) pm = fmaxf(pm, fmaxf(sa0[r], sa1[r]));
    pm = fmaxf(pm, __shfl_xor(pm, 32));
    if (!__all(pm - m_run <= 8.0f)) {
      float mnew = fmaxf(m_run, pm);
      float corr = EXP2(m_run - mnew);
      l_run *= corr;
#pragma unroll
      for (int r = 0; r < 16; r++) { oa0[r] *= corr; oa1[r] *= corr; }
      m_run = mnew;
    }
    float lsum = 0.f;
#pragma unroll
    for (int r = 0; r < 16; r++) {
      float e0 = EXP2(sa0[r] - m_run); sa0[r] = e0;
      float e1 = EXP2(sa1[r] - m_run); sa1[r] = e1;
      lsum += e0 + e1;
    }
    lsum += __shfl_xor(lsum, 32);
    l_run += lsum;
    // pack P^T into PV B-fragments via cvt_pk + half-swap
    u32 Aw[8], Bw_[8], Asw[8], Bsw[8];
#pragma unroll
    for (int r2 = 0; r2 < 4; r2++) {
      Aw[r2]      = cvtpk(sa0[4 * r2 + 0], sa0[4 * r2 + 1]);
      Bw_[r2]     = cvtpk(sa0[4 * r2 + 2], sa0[4 * r2 + 3]);
      Aw[4 + r2]  = cvtpk(sa1[4 * r2 + 0], sa1[4 * r2 + 1]);
      Bw_[4 + r2] = cvtpk(sa1[4 * r2 + 2], sa1[4 * r2 + 3]);
    }
#pragma unroll
    for (int i = 0; i < 8; i++) {
      Asw[i] = __shfl_xor(Aw[i], 32);
      Bsw[i] = __shfl_xor(Bw_[i], 32);
    }
    // O^T += V^T . P^T
#pragma unroll
    for (int ks = 0; ks < 4; ks++) {
      int mo = (ks >> 1) * 4;
      int r2e = mo + 2 * (ks & 1), r2o = r2e + 1;
      union { u32 wd[4]; bf16x8 v; } u;
      u.wd[0] = hh ? Asw[r2o] : Aw[r2e];
      u.wd[1] = hh ? Bsw[r2o] : Bw_[r2e];
      u.wd[2] = hh ? Aw[r2o]  : Asw[r2e];
      u.wd[3] = hh ? Bw_[r2o] : Bsw[r2e];
      bf16x8 va = *(const bf16x8*)&Vb[lsw(c,      ks * 16 + hh * 8)];
      bf16x8 vb = *(const bf16x8*)&Vb[lsw(32 + c, ks * 16 + hh * 8)];
      oa0 = __builtin_amdgcn_mfma_f32_32x32x16_bf16(va, u.v, oa0, 0, 0, 0);
      oa1 = __builtin_amdgcn_mfma_f32_32x32x16_bf16(vb, u.v, oa1, 0, 0, 0);
    }
  }
  float invl = 1.0f / l_run;
  u16* orow = outp + ((size_t)b * T_ + q_abs) * DM + hd * 64;
#pragma unroll
  for (int g = 0; g < 4; g++) {
    uint2 s0, s1;
    s0.x = cvtpk(oa0[4*g+0] * invl, oa0[4*g+1] * invl);
    s0.y = cvtpk(oa0[4*g+2] * invl, oa0[4*g+3] * invl);
    s1.x = cvtpk(oa1[4*g+0] * invl, oa1[4*g+1] * invl);
    s1.y = cvtpk(oa1[4*g+2] * invl, oa1[4*g+3] * invl);
    int d0 = g * 8 + hh * 4;
    *(uint2*)(orow + d0)      = s0;
    *(uint2*)(orow + 32 + d0) = s1;
  }
}

// ---------------- head: out = lnf(bf16) @ head_w + head_b, N=64 ----------------
__global__ __launch_bounds__(256) void head_k(
    const u16* __restrict__ xb, const float* __restrict__ W,
    const float* __restrict__ bias, float* __restrict__ out) {
  int wid = threadIdx.x >> 6, lane = threadIdx.x & 63;
  int row = blockIdx.x * 4 + wid;
  const u16* xr = xb + (size_t)row * DM;
  float a0 = 0.f, a1 = 0.f, a2 = 0.f, a3 = 0.f;
  for (int d = 0; d < DM; d += 8) {
    uint4 xv = *(const uint4*)(xr + d);
    const u16* xp = (const u16*)&xv;
    const float* Wp = W + (size_t)d * 64 + lane;
    a0 += b2f(xp[0]) * Wp[0];
    a1 += b2f(xp[1]) * Wp[64];
    a2 += b2f(xp[2]) * Wp[128];
    a3 += b2f(xp[3]) * Wp[192];
    a0 += b2f(xp[4]) * Wp[256];
    a1 += b2f(xp[5]) * Wp[320];
    a2 += b2f(xp[6]) * Wp[384];
    a3 += b2f(xp[7]) * Wp[448];
  }
  out[(size_t)row * 64 + lane] = a0 + a1 + a2 + a3 + bias[lane];
}

extern "C" void kernel_launch(void* const* d_in, const int* in_sizes, int n_in,
                              void* d_out, int out_size, void* d_ws, size_t ws_size,
                              hipStream_t stream) {
  (void)in_sizes; (void)n_in; (void)out_size; (void)ws_size;
  const float* x_in  = (const float*)d_in[0];
  const float* inp_w = (const float*)d_in[1];
  const float* inp_b = (const float*)d_in[2];
  const float* pos   = (const float*)d_in[3];
  const float* ln1g  = (const float*)d_in[4];
  const float* ln1b  = (const float*)d_in[5];
  const float* qkvw  = (const float*)d_in[6];
  const float* projw = (const float*)d_in[7];
  const float* ln2g  = (const float*)d_in[8];
  const float* ln2b  = (const float*)d_in[9];
  const float* fc1w  = (const float*)d_in[10];
  const float* fc2w  = (const float*)d_in[11];
  const float* lnfg  = (const float*)d_in[12];
  const float* lnfb  = (const float*)d_in[13];
  const float* headw = (const float*)d_in[14];
  const float* headb = (const float*)d_in[15];

  char* ws = (char*)d_ws;
  size_t off = 0;
  float* x    = (float*)(ws + off); off += (size_t)MTOT * DM * 4;
  u16*  lnb   = (u16*)(ws + off);   off += (size_t)MTOT * DM * 2;
  u16*  qkvb  = (u16*)(ws + off);   off += (size_t)MTOT * 3 * DM * 2;
  u16*  attno = (u16*)(ws + off);   off += (size_t)MTOT * DM * 2;
  u16*  ff    = qkvb;  // reuses qkv+attno regions
  u16*  qkvt  = (u16*)(ws + off);   off += (size_t)4 * DM * 3 * DM * 2;
  u16*  projt = (u16*)(ws + off);   off += (size_t)4 * DM * DM * 2;
  u16*  fc1t  = (u16*)(ws + off);   off += (size_t)4 * DM * DFF * 2;
  u16*  fc2t  = (u16*)(ws + off);   off += (size_t)4 * DFF * DM * 2;

  wconv_k<<<dim3(16, 48, 4), 256, 0, stream>>>(qkvw,  qkvt, DM, 3 * DM);
  wconv_k<<<dim3(16, 16, 4), 256, 0, stream>>>(projw, projt, DM, DM);
  wconv_k<<<dim3(16, 64, 4), 256, 0, stream>>>(fc1w,  fc1t, DM, DFF);
  wconv_k<<<dim3(64, 16, 4), 256, 0, stream>>>(fc2w,  fc2t, DFF, DM);

  embed_k<<<(MTOT * DM) / 256, 256, 0, stream>>>(x_in, inp_w, inp_b, pos, x);
  for (int ly = 0; ly < 4; ly++) {
    ln_k<<<MTOT / 4, 256, 0, stream>>>(x, ln1g + ly * DM, ln1b + ly * DM, lnb);
    gemm_k<0><<<dim3(12, 64), 256, 0, stream>>>(lnb, qkvt + (size_t)ly * DM * 3 * DM,
                                                qkvb, nullptr, MTOT, 3 * DM, DM, DM);
    attn_k<<<dim3(T_ / 128, B_ * NH), 256, 0, stream>>>(qkvb, attno);
    gemm_k<1><<<dim3(4, 64), 256, 0, stream>>>(attno, projt + (size_t)ly * DM * DM,
                                               nullptr, x, MTOT, DM, DM, 0);
    ln_k<<<MTOT / 4, 256, 0, stream>>>(x, ln2g + ly * DM, ln2b + ly * DM, lnb);
    gemm_k<2><<<dim3(16, 64), 256, 0, stream>>>(lnb, fc1t + (size_t)ly * DM * DFF,
                                                ff, nullptr, MTOT, DFF, DM, 0);
    gemm_k<1><<<dim3(4, 64), 256, 0, stream>>>(ff, fc2t + (size_t)ly * DFF * DM,
                                               nullptr, x, MTOT, DM, DFF, 0);
  }
  ln_k<<<MTOT / 4, 256, 0, stream>>>(x, lnfg, lnfb, lnb);
  head_k<<<MTOT / 4, 256, 0, stream>>>(lnb, headw, headb, (float*)d_out);
}

// Round 4
// 1045.475 us; speedup vs baseline: 6.0392x; 1.1368x over previous
//
#include <hip/hip_runtime.h>
#include <math.h>

typedef unsigned short u16;
typedef unsigned int u32;

#define B_ 2
#define T_ 4096
#define DM 512
#define NH 8
#define DH 64
#define DFF 2048
#define MTOT (B_*T_)   // 8192

// Q pre-scale: (1/sqrt(64)) * log2(e)  -> softmax runs in exp2 domain
#define SCALEQ 0.18033688011112042f

using f32x4  = __attribute__((ext_vector_type(4))) float;
using f32x16 = __attribute__((ext_vector_type(16))) float;
using bf16x8 = __attribute__((ext_vector_type(8))) short;

__device__ __forceinline__ float b2f(u16 u) {
  union { u32 u; float f; } v; v.u = ((u32)u) << 16; return v.f;
}
__device__ __forceinline__ u16 f2b(float f) {
  union { float f; u32 u; } v; v.f = f;
  u32 r = v.u + 0x7FFFu + ((v.u >> 16) & 1u);
  return (u16)(r >> 16);
}
// packed f32 pair -> bf16 pair (RTNE), single VALU op
__device__ __forceinline__ u32 cvtpk(float lo, float hi) {
  u32 r;
  asm("v_cvt_pk_bf16_f32 %0, %1, %2" : "=v"(r) : "v"(lo), "v"(hi));
  return r;
}
#if __has_builtin(__builtin_amdgcn_exp2f)
#define EXP2(x) __builtin_amdgcn_exp2f(x)
#else
#define EXP2(x) __expf((x) * 0.6931471805599453f)
#endif
#if __has_builtin(__builtin_amdgcn_rcpf)
#define RCP(x) __builtin_amdgcn_rcpf(x)
#else
#define RCP(x) (1.0f / (x))
#endif

// async global->LDS, 16B per lane, dest = uniform base + lane*16
__device__ __forceinline__ void gload_lds(const u16* g, u16* l) {
  __builtin_amdgcn_global_load_lds(
      (const __attribute__((address_space(1))) void*)g,
      (__attribute__((address_space(3))) void*)l, 16, 0, 0);
}

// LDS swizzle for [64][64] u16 tiles (128B rows). Returns u16 element offset.
__device__ __forceinline__ int lsw(int row, int col) {
  int slot = ((col >> 3) + (row >> 3) + 2 * (row & 7)) & 7;
  return (row << 6) + (slot << 3) + (col & 7);
}

// ---------------- embed ----------------
__global__ __launch_bounds__(256) void embed_k(
    const float* __restrict__ x_in, const float* __restrict__ w,
    const float* __restrict__ bias, const float* __restrict__ pos,
    float* __restrict__ x) {
  int idx = blockIdx.x * 256 + threadIdx.x;
  int row = idx >> 9, d = idx & 511;
  int t = row & (T_ - 1);
  x[idx] = x_in[row] * w[d] + bias[d] + pos[t * DM + d];
}

// ---------------- layernorm fp32 -> bf16 ----------------
__global__ __launch_bounds__(256) void ln_k(
    const float* __restrict__ x, const float* __restrict__ g,
    const float* __restrict__ bet, u16* __restrict__ y) {
  int wid = threadIdx.x >> 6, lane = threadIdx.x & 63;
  int row = blockIdx.x * 4 + wid;
  const float* xr = x + (size_t)row * DM + lane * 8;
  float4 a0 = *(const float4*)xr;
  float4 a1 = *(const float4*)(xr + 4);
  float v[8] = {a0.x, a0.y, a0.z, a0.w, a1.x, a1.y, a1.z, a1.w};
  float s = 0.f;
#pragma unroll
  for (int j = 0; j < 8; j++) s += v[j];
#pragma unroll
  for (int off = 32; off; off >>= 1) s += __shfl_xor(s, off);
  float mu = s * (1.0f / DM);
  float q = 0.f;
#pragma unroll
  for (int j = 0; j < 8; j++) { float e = v[j] - mu; q += e * e; }
#pragma unroll
  for (int off = 32; off; off >>= 1) q += __shfl_xor(q, off);
  float rs = rsqrtf(q * (1.0f / DM) + 1e-5f);
  float4 g0 = *(const float4*)(g + lane * 8);
  float4 g1 = *(const float4*)(g + lane * 8 + 4);
  float4 p0 = *(const float4*)(bet + lane * 8);
  float4 p1 = *(const float4*)(bet + lane * 8 + 4);
  float gg[8] = {g0.x, g0.y, g0.z, g0.w, g1.x, g1.y, g1.z, g1.w};
  float pp[8] = {p0.x, p0.y, p0.z, p0.w, p1.x, p1.y, p1.z, p1.w};
  uint4 st;
  st.x = cvtpk((v[0]-mu)*rs*gg[0]+pp[0], (v[1]-mu)*rs*gg[1]+pp[1]);
  st.y = cvtpk((v[2]-mu)*rs*gg[2]+pp[2], (v[3]-mu)*rs*gg[3]+pp[3]);
  st.z = cvtpk((v[4]-mu)*rs*gg[4]+pp[4], (v[5]-mu)*rs*gg[5]+pp[5]);
  st.w = cvtpk((v[6]-mu)*rs*gg[6]+pp[6], (v[7]-mu)*rs*gg[7]+pp[7]);
  *(uint4*)(y + (size_t)row * DM + lane * 8) = st;
}

// ---------------- weight convert+transpose: W[K][N] fp32 -> Wt[N][K] bf16 ----
__global__ __launch_bounds__(256) void wconv_k(
    const float* __restrict__ W, u16* __restrict__ Wt, int K, int N) {
  __shared__ float tile[32][33];
  const float* Wl = W + (size_t)blockIdx.z * K * N;
  u16* Wtl = Wt + (size_t)blockIdx.z * K * N;
  int k0 = blockIdx.x * 32, n0 = blockIdx.y * 32;
  int r = threadIdx.x >> 3, c4 = (threadIdx.x & 7) * 4;
  *(float4*)&tile[r][c4] = *(const float4*)(Wl + (size_t)(k0 + r) * N + n0 + c4);
  __syncthreads();
  uint2 st;
  st.x = cvtpk(tile[c4 + 0][r], tile[c4 + 1][r]);
  st.y = cvtpk(tile[c4 + 2][r], tile[c4 + 3][r]);
  *(uint2*)(Wtl + (size_t)(n0 + r) * K + k0 + c4) = st;
}

// ---------------- bf16 MFMA GEMM: C[M,N] = A[M,K] @ Bt[N,K]^T ----------------
// 2-phase double-buffered: prefetch K-step k+1 (global_load_lds) issued BEFORE
// computing step k; single barrier per step (vmcnt drained by __syncthreads).
// EPI: 0 = store bf16 (cols < scale_cols get *SCALEQ), 1 = Cf += acc, 2 = gelu->bf16
template<int EPI>
__global__ __launch_bounds__(256) void gemm_k(
    const u16* __restrict__ A, const u16* __restrict__ Bt,
    u16* __restrict__ Cb, float* __restrict__ Cf,
    int M, int N, int K, int scale_cols) {
  __shared__ u16 As[2][128][32];
  __shared__ u16 Bs[2][128][32];   // Bs[buf][n][k]
  int tid = threadIdx.x;
  int lane = tid & 63, wid = tid >> 6;
  int wr = wid >> 1, wc = wid & 1;
  int m0 = blockIdx.y * 128, n0 = blockIdx.x * 128;
  f32x4 acc[4][4] = {};
  int rsub = lane >> 2, ksub = (lane & 3) * 8;
  const u16* Ab = A  + (size_t)(m0 + wid * 32 + rsub) * K + ksub;
  const u16* Bb = Bt + (size_t)(n0 + wid * 32 + rsub) * K + ksub;
#define GSTAGE(BUF, KO) { \
    gload_lds(Ab + (KO), &As[BUF][wid * 32][0]); \
    gload_lds(Ab + (size_t)16 * K + (KO), &As[BUF][wid * 32 + 16][0]); \
    gload_lds(Bb + (KO), &Bs[BUF][wid * 32][0]); \
    gload_lds(Bb + (size_t)16 * K + (KO), &Bs[BUF][wid * 32 + 16][0]); }
  GSTAGE(0, 0);
  __syncthreads();
  int r = lane & 15, kc = (lane >> 4) * 8;
  for (int k0 = 0; k0 < K; k0 += 32) {
    int cur = (k0 >> 5) & 1;
    if (k0 + 32 < K) GSTAGE(cur ^ 1, k0 + 32);
    bf16x8 af[4], bfr[4];
#pragma unroll
    for (int m = 0; m < 4; m++) af[m]  = *(const bf16x8*)&As[cur][wr*64 + m*16 + r][kc];
#pragma unroll
    for (int n = 0; n < 4; n++) bfr[n] = *(const bf16x8*)&Bs[cur][wc*64 + n*16 + r][kc];
#pragma unroll
    for (int m = 0; m < 4; m++)
#pragma unroll
      for (int n = 0; n < 4; n++)
        acc[m][n] = __builtin_amdgcn_mfma_f32_16x16x32_bf16(af[m], bfr[n], acc[m][n], 0, 0, 0);
    __syncthreads();
  }
  int r4 = (lane >> 4) * 4, cN = lane & 15;
#pragma unroll
  for (int m = 0; m < 4; m++) {
#pragma unroll
    for (int n = 0; n < 4; n++) {
      int col = n0 + wc*64 + n*16 + cN;
#pragma unroll
      for (int i = 0; i < 4; i++) {
        int row = m0 + wr*64 + m*16 + r4 + i;
        size_t off = (size_t)row * N + col;
        float v = acc[m][n][i];
        if (EPI == 0) {
          if (col < scale_cols) v *= SCALEQ;
          Cb[off] = f2b(v);
        } else if (EPI == 1) {
          Cf[off] += v;
        } else {
          float e = EXP2(v * (2.3022082f + 0.10294324f * v * v));
          Cb[off] = f2b(v * (1.0f - RCP(e + 1.0f)));
        }
      }
    }
  }
}

// ---------------- MFMA causal flash attention, balanced K-split ----------------
// Each 128-row q-block (qb) is split into nc = qb/8+1 chunk-blocks over its
// kv-range. grid (80, 16) = 1280 blocks (5/CU). Chunks write unnormalized
// O~ (bf16) + (m,l) partials; comb_k merges. XCD-bijective swizzle keeps all
// 80 chunks of one (b,head) on one XCD for K/V L2 reuse.
__global__ __launch_bounds__(256) void attn_k(const u16* __restrict__ qkv,
                                              u16* __restrict__ Opart,
                                              float* __restrict__ ml) {
  __shared__ u16 Ks[2][64 * 64];
  __shared__ u16 Vt[2][64 * 64];
  int tid = threadIdx.x;
  int w = tid >> 6, l = tid & 63;
  int hh = l >> 5, c = l & 31;
  int flat = blockIdx.y * 80 + blockIdx.x;
  int swz = (flat & 7) * 160 + (flat >> 3);      // XCD-contiguous bh groups
  int bh = swz / 80, slot = swz - bh * 80;
  int qb, ck, nc;
  if (slot < 8)       { qb = slot;                 ck = 0;                nc = 1; }
  else if (slot < 24) { int s = slot - 8;  qb = 8 + (s >> 1);  ck = s & 1; nc = 2; }
  else if (slot < 48) { int s = slot - 24; qb = 16 + s / 3;    ck = s - (qb - 16) * 3; nc = 3; }
  else                { int s = slot - 48; qb = 24 + (s >> 2); ck = s & 3; nc = 4; }
  int ntot = 2 * qb + 2;
  int kt0 = ck * ntot / nc, kt1 = (ck + 1) * ntot / nc;
  int b = bh >> 3, hd = bh & 7;
  int q0w = qb * 128 + w * 32;
  int q_abs = q0w + c;
  size_t base = (size_t)b * T_ * 1536;
  bf16x8 qf[4];
  const u16* qp = qkv + base + (size_t)q_abs * 1536 + hd * 64 + hh * 8;
#pragma unroll
  for (int kk = 0; kk < 4; kk++) qf[kk] = *(const bf16x8*)(qp + kk * 16);
  f32x16 oa0 = {}, oa1 = {};
  float m_run = -1e30f, l_run = 0.f;
  int sp = tid >> 3, d8 = (tid & 7) * 8;
  int r0 = sp * 2, r1 = r0 + 1;
  const u16* kvbase = qkv + base + DM + hd * 64 + d8;
  uint4 kreg0, kreg1, vreg0, vreg1;
#define AGLOAD(KT) { \
    const u16* s0_ = kvbase + (size_t)((KT) * 64 + r0) * 1536; \
    kreg0 = *(const uint4*)s0_; vreg0 = *(const uint4*)(s0_ + DM); \
    const u16* s1_ = s0_ + 1536; \
    kreg1 = *(const uint4*)s1_; vreg1 = *(const uint4*)(s1_ + DM); }
  AGLOAD(kt0);
  for (int kt = kt0; kt < kt1; kt++) {
    u16* Kb = Ks[kt & 1];
    u16* Vb = Vt[kt & 1];
    *(uint4*)&Kb[lsw(r0, d8)] = kreg0;
    *(uint4*)&Kb[lsw(r1, d8)] = kreg1;
    {
      const u16* v0 = (const u16*)&vreg0;
      const u16* v1 = (const u16*)&vreg1;
#pragma unroll
      for (int j = 0; j < 8; j++) {
        u32 pw = (u32)v0[j] | ((u32)v1[j] << 16);
        *(u32*)&Vb[lsw(d8 + j, r0)] = pw;
      }
    }
    if (kt + 1 < kt1) AGLOAD(kt + 1);
    __syncthreads();
    if (kt * 64 > q0w + 31) continue;  // fully masked for this wave
    bool needMask = (kt * 64 + 63 > q0w);
    f32x16 sa0 = {}, sa1 = {};
#pragma unroll
    for (int kk = 0; kk < 4; kk++) {
      bf16x8 ka  = *(const bf16x8*)&Kb[lsw(c,      kk * 16 + hh * 8)];
      bf16x8 kb2 = *(const bf16x8*)&Kb[lsw(32 + c, kk * 16 + hh * 8)];
      sa0 = __builtin_amdgcn_mfma_f32_32x32x16_bf16(ka,  qf[kk], sa0, 0, 0, 0);
      sa1 = __builtin_amdgcn_mfma_f32_32x32x16_bf16(kb2, qf[kk], sa1, 0, 0, 0);
    }
    if (needMask) {
#pragma unroll
      for (int g = 0; g < 4; g++)
#pragma unroll
        for (int i = 0; i < 4; i++) {
          int krow = kt * 64 + g * 8 + hh * 4 + i;
          if (krow > q_abs)      sa0[g * 4 + i] = -1e30f;
          if (krow + 32 > q_abs) sa1[g * 4 + i] = -1e30f;
        }
    }
    float pm = -1e30f;
#pragma unroll
    for (int r = 0; r < 16; r++) pm = fmaxf(pm, fmaxf(sa0[r], sa1[r]));
    pm = fmaxf(pm, __shfl_xor(pm, 32));
    if (!__all(pm - m_run <= 8.0f)) {
      float mnew = fmaxf(m_run, pm);
      float corr = EXP2(m_run - mnew);
      l_run *= corr;
#pragma unroll
      for (int r = 0; r < 16; r++) { oa0[r] *= corr; oa1[r] *= corr; }
      m_run = mnew;
    }
    float lsum = 0.f;
#pragma unroll
    for (int r = 0; r < 16; r++) {
      float e0 = EXP2(sa0[r] - m_run); sa0[r] = e0;
      float e1 = EXP2(sa1[r] - m_run); sa1[r] = e1;
      lsum += e0 + e1;
    }
    lsum += __shfl_xor(lsum, 32);
    l_run += lsum;
    u32 Aw[8], Bw_[8], Asw[8], Bsw[8];
#pragma unroll
    for (int r2 = 0; r2 < 4; r2++) {
      Aw[r2]      = cvtpk(sa0[4 * r2 + 0], sa0[4 * r2 + 1]);
      Bw_[r2]     = cvtpk(sa0[4 * r2 + 2], sa0[4 * r2 + 3]);
      Aw[4 + r2]  = cvtpk(sa1[4 * r2 + 0], sa1[4 * r2 + 1]);
      Bw_[4 + r2] = cvtpk(sa1[4 * r2 + 2], sa1[4 * r2 + 3]);
    }
#pragma unroll
    for (int i = 0; i < 8; i++) {
      Asw[i] = __shfl_xor(Aw[i], 32);
      Bsw[i] = __shfl_xor(Bw_[i], 32);
    }
#pragma unroll
    for (int ks = 0; ks < 4; ks++) {
      int mo = (ks >> 1) * 4;
      int r2e = mo + 2 * (ks & 1), r2o = r2e + 1;
      union { u32 wd[4]; bf16x8 v; } u;
      u.wd[0] = hh ? Asw[r2o] : Aw[r2e];
      u.wd[1] = hh ? Bsw[r2o] : Bw_[r2e];
      u.wd[2] = hh ? Aw[r2o]  : Asw[r2e];
      u.wd[3] = hh ? Bw_[r2o] : Bsw[r2e];
      bf16x8 va = *(const bf16x8*)&Vb[lsw(c,      ks * 16 + hh * 8)];
      bf16x8 vb = *(const bf16x8*)&Vb[lsw(32 + c, ks * 16 + hh * 8)];
      oa0 = __builtin_amdgcn_mfma_f32_32x32x16_bf16(va, u.v, oa0, 0, 0, 0);
      oa1 = __builtin_amdgcn_mfma_f32_32x32x16_bf16(vb, u.v, oa1, 0, 0, 0);
    }
  }
  // write unnormalized partial
  int sidx = bh * 80 + slot;
  u16* op = Opart + ((size_t)sidx * 128 + w * 32 + c) * 64;
#pragma unroll
  for (int g = 0; g < 4; g++) {
    uint2 s0, s1;
    s0.x = cvtpk(oa0[4*g+0], oa0[4*g+1]);
    s0.y = cvtpk(oa0[4*g+2], oa0[4*g+3]);
    s1.x = cvtpk(oa1[4*g+0], oa1[4*g+1]);
    s1.y = cvtpk(oa1[4*g+2], oa1[4*g+3]);
    int d0 = g * 8 + hh * 4;
    *(uint2*)(op + d0)      = s0;
    *(uint2*)(op + 32 + d0) = s1;
  }
  if (hh == 0) {
    float2 p; p.x = m_run; p.y = l_run;
    *(float2*)&ml[((size_t)sidx * 128 + w * 32 + c) * 2] = p;
  }
}

// ---------------- combine partials -> attno ----------------
__global__ __launch_bounds__(256) void comb_k(
    const u16* __restrict__ Opart, const float* __restrict__ ml,
    u16* __restrict__ attno) {
  int g = blockIdx.x * 256 + threadIdx.x;     // 16*4096*64
  int d = g & 63, bhq = g >> 6;
  int bh = bhq >> 12, q = bhq & 4095;
  int qb = q >> 7, ri = q & 127;
  int bs, nc;
  if (qb < 8)       { bs = qb;                  nc = 1; }
  else if (qb < 16) { bs = 8 + ((qb - 8) << 1); nc = 2; }
  else if (qb < 24) { bs = 24 + (qb - 16) * 3;  nc = 3; }
  else              { bs = 48 + ((qb - 24) << 2); nc = 4; }
  int s0 = bh * 80 + bs;
  float m[4], lv[4], M = -1e30f;
  for (int cc = 0; cc < nc; cc++) {
    float2 p = *(const float2*)&ml[((size_t)(s0 + cc) * 128 + ri) * 2];
    m[cc] = p.x; lv[cc] = p.y;
    M = fmaxf(M, p.x);
  }
  float O = 0.f, L = 0.f;
  for (int cc = 0; cc < nc; cc++) {
    float wgt = EXP2(m[cc] - M);
    L += lv[cc] * wgt;
    O += b2f(Opart[((size_t)(s0 + cc) * 128 + ri) * 64 + d]) * wgt;
  }
  int b = bh >> 3, hd = bh & 7;
  attno[((size_t)b * T_ + q) * DM + hd * 64 + d] = f2b(O / L);
}

// ---------------- head: out = lnf(bf16) @ head_w + head_b, N=64 ----------------
__global__ __launch_bounds__(256) void head_k(
    const u16* __restrict__ xb, const float* __restrict__ W,
    const float* __restrict__ bias, float* __restrict__ out) {
  int wid = threadIdx.x >> 6, lane = threadIdx.x & 63;
  int row = blockIdx.x * 4 + wid;
  const u16* xr = xb + (size_t)row * DM;
  float a0 = 0.f, a1 = 0.f, a2 = 0.f, a3 = 0.f;
  for (int d = 0; d < DM; d += 8) {
    uint4 xv = *(const uint4*)(xr + d);
    const u16* xp = (const u16*)&xv;
    const float* Wp = W + (size_t)d * 64 + lane;
    a0 += b2f(xp[0]) * Wp[0];
    a1 += b2f(xp[1]) * Wp[64];
    a2 += b2f(xp[2]) * Wp[128];
    a3 += b2f(xp[3]) * Wp[192];
    a0 += b2f(xp[4]) * Wp[256];
    a1 += b2f(xp[5]) * Wp[320];
    a2 += b2f(xp[6]) * Wp[384];
    a3 += b2f(xp[7]) * Wp[448];
  }
  out[(size_t)row * 64 + lane] = a0 + a1 + a2 + a3 + bias[lane];
}

extern "C" void kernel_launch(void* const* d_in, const int* in_sizes, int n_in,
                              void* d_out, int out_size, void* d_ws, size_t ws_size,
                              hipStream_t stream) {
  (void)in_sizes; (void)n_in; (void)out_size; (void)ws_size;
  const float* x_in  = (const float*)d_in[0];
  const float* inp_w = (const float*)d_in[1];
  const float* inp_b = (const float*)d_in[2];
  const float* pos   = (const float*)d_in[3];
  const float* ln1g  = (const float*)d_in[4];
  const float* ln1b  = (const float*)d_in[5];
  const float* qkvw  = (const float*)d_in[6];
  const float* projw = (const float*)d_in[7];
  const float* ln2g  = (const float*)d_in[8];
  const float* ln2b  = (const float*)d_in[9];
  const float* fc1w  = (const float*)d_in[10];
  const float* fc2w  = (const float*)d_in[11];
  const float* lnfg  = (const float*)d_in[12];
  const float* lnfb  = (const float*)d_in[13];
  const float* headw = (const float*)d_in[14];
  const float* headb = (const float*)d_in[15];

  char* ws = (char*)d_ws;
  size_t off = 0;
  float* x     = (float*)(ws + off); off += (size_t)MTOT * DM * 4;
  u16*  lnb    = (u16*)(ws + off);   off += (size_t)MTOT * DM * 2;
  u16*  qkvb   = (u16*)(ws + off);   off += (size_t)MTOT * 3 * DM * 2;
  u16*  attno  = (u16*)(ws + off);   off += (size_t)MTOT * DM * 2;
  u16*  ff     = qkvb;  // reuses qkv+attno regions
  u16*  qkvt   = (u16*)(ws + off);   off += (size_t)4 * DM * 3 * DM * 2;
  u16*  projt  = (u16*)(ws + off);   off += (size_t)4 * DM * DM * 2;
  u16*  fc1t   = (u16*)(ws + off);   off += (size_t)4 * DM * DFF * 2;
  u16*  fc2t   = (u16*)(ws + off);   off += (size_t)4 * DFF * DM * 2;
  u16*  Opart  = (u16*)(ws + off);   off += (size_t)16 * 80 * 128 * 64 * 2;  // 21 MB
  float* mlbuf = (float*)(ws + off); off += (size_t)16 * 80 * 128 * 2 * 4;   // 1.3 MB

  wconv_k<<<dim3(16, 48, 4), 256, 0, stream>>>(qkvw,  qkvt, DM, 3 * DM);
  wconv_k<<<dim3(16, 16, 4), 256, 0, stream>>>(projw, projt, DM, DM);
  wconv_k<<<dim3(16, 64, 4), 256, 0, stream>>>(fc1w,  fc1t, DM, DFF);
  wconv_k<<<dim3(64, 16, 4), 256, 0, stream>>>(fc2w,  fc2t, DFF, DM);

  embed_k<<<(MTOT * DM) / 256, 256, 0, stream>>>(x_in, inp_w, inp_b, pos, x);
  for (int ly = 0; ly < 4; ly++) {
    ln_k<<<MTOT / 4, 256, 0, stream>>>(x, ln1g + ly * DM, ln1b + ly * DM, lnb);
    gemm_k<0><<<dim3(12, 64), 256, 0, stream>>>(lnb, qkvt + (size_t)ly * DM * 3 * DM,
                                                qkvb, nullptr, MTOT, 3 * DM, DM, DM);
    attn_k<<<dim3(80, 16), 256, 0, stream>>>(qkvb, Opart, mlbuf);
    comb_k<<<(16 * 4096 * 64) / 256, 256, 0, stream>>>(Opart, mlbuf, attno);
    gemm_k<1><<<dim3(4, 64), 256, 0, stream>>>(attno, projt + (size_t)ly * DM * DM,
                                               nullptr, x, MTOT, DM, DM, 0);
    ln_k<<<MTOT / 4, 256, 0, stream>>>(x, ln2g + ly * DM, ln2b + ly * DM, lnb);
    gemm_k<2><<<dim3(16, 64), 256, 0, stream>>>(lnb, fc1t + (size_t)ly * DM * DFF,
                                                ff, nullptr, MTOT, DFF, DM, 0);
    gemm_k<1><<<dim3(4, 64), 256, 0, stream>>>(ff, fc2t + (size_t)ly * DFF * DM,
                                               nullptr, x, MTOT, DM, DFF, 0);
  }
  ln_k<<<MTOT / 4, 256, 0, stream>>>(x, lnfg, lnfb, lnb);
  head_k<<<MTOT / 4, 256, 0, stream>>>(lnb, headw, headb, (float*)d_out);
}

// Round 5
// 1024.856 us; speedup vs baseline: 6.1607x; 1.0201x over previous
//
#include <hip/hip_runtime.h>
#include <math.h>

typedef unsigned short u16;
typedef unsigned int u32;

#define B_ 2
#define T_ 4096
#define DM 512
#define NH 8
#define DH 64
#define DFF 2048
#define MTOT (B_*T_)   // 8192

// Q pre-scale: (1/sqrt(64)) * log2(e)  -> softmax runs in exp2 domain
#define SCALEQ 0.18033688011112042f

using f32x4  = __attribute__((ext_vector_type(4))) float;
using f32x16 = __attribute__((ext_vector_type(16))) float;
using bf16x8 = __attribute__((ext_vector_type(8))) short;

__device__ __forceinline__ float b2f(u16 u) {
  union { u32 u; float f; } v; v.u = ((u32)u) << 16; return v.f;
}
__device__ __forceinline__ u16 f2b(float f) {
  union { float f; u32 u; } v; v.f = f;
  u32 r = v.u + 0x7FFFu + ((v.u >> 16) & 1u);
  return (u16)(r >> 16);
}
// packed f32 pair -> bf16 pair (RTNE), single VALU op
__device__ __forceinline__ u32 cvtpk(float lo, float hi) {
  u32 r;
  asm("v_cvt_pk_bf16_f32 %0, %1, %2" : "=v"(r) : "v"(lo), "v"(hi));
  return r;
}
#if __has_builtin(__builtin_amdgcn_exp2f)
#define EXP2(x) __builtin_amdgcn_exp2f(x)
#else
#define EXP2(x) __expf((x) * 0.6931471805599453f)
#endif
#if __has_builtin(__builtin_amdgcn_rcpf)
#define RCP(x) __builtin_amdgcn_rcpf(x)
#else
#define RCP(x) (1.0f / (x))
#endif

// async global->LDS, 16B per lane, dest = uniform base + lane*16
__device__ __forceinline__ void gload_lds(const u16* g, u16* l) {
  __builtin_amdgcn_global_load_lds(
      (const __attribute__((address_space(1))) void*)g,
      (__attribute__((address_space(3))) void*)l, 16, 0, 0);
}

// LDS swizzle for [64][64] u16 tiles (128B rows). Returns u16 element offset.
__device__ __forceinline__ int lsw(int row, int col) {
  int slot = ((col >> 3) + (row >> 3) + 2 * (row & 7)) & 7;
  return (row << 6) + (slot << 3) + (col & 7);
}

// ---------------- embed ----------------
__global__ __launch_bounds__(256) void embed_k(
    const float* __restrict__ x_in, const float* __restrict__ w,
    const float* __restrict__ bias, const float* __restrict__ pos,
    float* __restrict__ x) {
  int idx = blockIdx.x * 256 + threadIdx.x;
  int row = idx >> 9, d = idx & 511;
  int t = row & (T_ - 1);
  x[idx] = x_in[row] * w[d] + bias[d] + pos[t * DM + d];
}

// ---------------- layernorm (+ optional NP fp32 partial-adds into x) ----------
template<int NP>
__global__ __launch_bounds__(256) void ln_k(
    float* __restrict__ x, const float* __restrict__ P,
    const float* __restrict__ g, const float* __restrict__ bet,
    u16* __restrict__ y) {
  int wid = threadIdx.x >> 6, lane = threadIdx.x & 63;
  int row = blockIdx.x * 4 + wid;
  float* xr = x + (size_t)row * DM + lane * 8;
  float4 a0 = *(const float4*)xr;
  float4 a1 = *(const float4*)(xr + 4);
  float v[8] = {a0.x, a0.y, a0.z, a0.w, a1.x, a1.y, a1.z, a1.w};
  if (NP > 0) {
#pragma unroll
    for (int s = 0; s < NP; s++) {
      const float* pr = P + (size_t)s * MTOT * DM + (size_t)row * DM + lane * 8;
      float4 p0 = *(const float4*)pr;
      float4 p1 = *(const float4*)(pr + 4);
      v[0] += p0.x; v[1] += p0.y; v[2] += p0.z; v[3] += p0.w;
      v[4] += p1.x; v[5] += p1.y; v[6] += p1.z; v[7] += p1.w;
    }
    float4 w0; w0.x = v[0]; w0.y = v[1]; w0.z = v[2]; w0.w = v[3];
    float4 w1; w1.x = v[4]; w1.y = v[5]; w1.z = v[6]; w1.w = v[7];
    *(float4*)xr = w0;
    *(float4*)(xr + 4) = w1;
  }
  float s = 0.f;
#pragma unroll
  for (int j = 0; j < 8; j++) s += v[j];
#pragma unroll
  for (int off = 32; off; off >>= 1) s += __shfl_xor(s, off);
  float mu = s * (1.0f / DM);
  float q = 0.f;
#pragma unroll
  for (int j = 0; j < 8; j++) { float e = v[j] - mu; q += e * e; }
#pragma unroll
  for (int off = 32; off; off >>= 1) q += __shfl_xor(q, off);
  float rs = rsqrtf(q * (1.0f / DM) + 1e-5f);
  float4 g0 = *(const float4*)(g + lane * 8);
  float4 g1 = *(const float4*)(g + lane * 8 + 4);
  float4 p0 = *(const float4*)(bet + lane * 8);
  float4 p1 = *(const float4*)(bet + lane * 8 + 4);
  float gg[8] = {g0.x, g0.y, g0.z, g0.w, g1.x, g1.y, g1.z, g1.w};
  float pp[8] = {p0.x, p0.y, p0.z, p0.w, p1.x, p1.y, p1.z, p1.w};
  uint4 st;
  st.x = cvtpk((v[0]-mu)*rs*gg[0]+pp[0], (v[1]-mu)*rs*gg[1]+pp[1]);
  st.y = cvtpk((v[2]-mu)*rs*gg[2]+pp[2], (v[3]-mu)*rs*gg[3]+pp[3]);
  st.z = cvtpk((v[4]-mu)*rs*gg[4]+pp[4], (v[5]-mu)*rs*gg[5]+pp[5]);
  st.w = cvtpk((v[6]-mu)*rs*gg[6]+pp[6], (v[7]-mu)*rs*gg[7]+pp[7]);
  *(uint4*)(y + (size_t)row * DM + lane * 8) = st;
}

// ---------------- weight convert+transpose: W[K][N] fp32 -> Wt[N][K] bf16 ----
__global__ __launch_bounds__(256) void wconv_k(
    const float* __restrict__ W, u16* __restrict__ Wt, int K, int N) {
  __shared__ float tile[32][33];
  const float* Wl = W + (size_t)blockIdx.z * K * N;
  u16* Wtl = Wt + (size_t)blockIdx.z * K * N;
  int k0 = blockIdx.x * 32, n0 = blockIdx.y * 32;
  int r = threadIdx.x >> 3, c4 = (threadIdx.x & 7) * 4;
  *(float4*)&tile[r][c4] = *(const float4*)(Wl + (size_t)(k0 + r) * N + n0 + c4);
  __syncthreads();
  uint2 st;
  st.x = cvtpk(tile[c4 + 0][r], tile[c4 + 1][r]);
  st.y = cvtpk(tile[c4 + 2][r], tile[c4 + 3][r]);
  *(uint2*)(Wtl + (size_t)(n0 + r) * K + k0 + c4) = st;
}

// ---------------- bf16 MFMA GEMM: C[M,N] = A[M,K] @ Bt[N,K]^T ----------------
// 2-phase double-buffered global_load_lds staging. blockIdx.z = K-slice
// (Kslice wide). EPI: 0 = bf16 store (cols<scale_cols *= SCALEQ),
// 1 = Cf += acc, 2 = gelu->bf16, 3 = Cf[slice] = acc (split-K partial).
template<int EPI>
__global__ __launch_bounds__(256) void gemm_k(
    const u16* __restrict__ A, const u16* __restrict__ Bt,
    u16* __restrict__ Cb, float* __restrict__ Cf,
    int M, int N, int K, int Kslice, int scale_cols) {
  __shared__ u16 As[2][128][32];
  __shared__ u16 Bs[2][128][32];   // Bs[buf][n][k]
  int tid = threadIdx.x;
  int lane = tid & 63, wid = tid >> 6;
  int wr = wid >> 1, wc = wid & 1;
  int m0 = blockIdx.y * 128, n0 = blockIdx.x * 128;
  int kbeg = blockIdx.z * Kslice;
  if (EPI == 3) Cf += (size_t)blockIdx.z * M * N;
  f32x4 acc[4][4] = {};
  int rsub = lane >> 2, ksub = (lane & 3) * 8;
  const u16* Ab = A  + (size_t)(m0 + wid * 32 + rsub) * K + kbeg + ksub;
  const u16* Bb = Bt + (size_t)(n0 + wid * 32 + rsub) * K + kbeg + ksub;
#define GSTAGE(BUF, KO) { \
    gload_lds(Ab + (KO), &As[BUF][wid * 32][0]); \
    gload_lds(Ab + (size_t)16 * K + (KO), &As[BUF][wid * 32 + 16][0]); \
    gload_lds(Bb + (KO), &Bs[BUF][wid * 32][0]); \
    gload_lds(Bb + (size_t)16 * K + (KO), &Bs[BUF][wid * 32 + 16][0]); }
  GSTAGE(0, 0);
  __syncthreads();
  int r = lane & 15, kc = (lane >> 4) * 8;
  for (int k0 = 0; k0 < Kslice; k0 += 32) {
    int cur = (k0 >> 5) & 1;
    if (k0 + 32 < Kslice) GSTAGE(cur ^ 1, k0 + 32);
    bf16x8 af[4], bfr[4];
#pragma unroll
    for (int m = 0; m < 4; m++) af[m]  = *(const bf16x8*)&As[cur][wr*64 + m*16 + r][kc];
#pragma unroll
    for (int n = 0; n < 4; n++) bfr[n] = *(const bf16x8*)&Bs[cur][wc*64 + n*16 + r][kc];
#pragma unroll
    for (int m = 0; m < 4; m++)
#pragma unroll
      for (int n = 0; n < 4; n++)
        acc[m][n] = __builtin_amdgcn_mfma_f32_16x16x32_bf16(af[m], bfr[n], acc[m][n], 0, 0, 0);
    __syncthreads();
  }
  int r4 = (lane >> 4) * 4, cN = lane & 15;
#pragma unroll
  for (int m = 0; m < 4; m++) {
#pragma unroll
    for (int n = 0; n < 4; n++) {
      int col = n0 + wc*64 + n*16 + cN;
#pragma unroll
      for (int i = 0; i < 4; i++) {
        int row = m0 + wr*64 + m*16 + r4 + i;
        size_t off = (size_t)row * N + col;
        float v = acc[m][n][i];
        if (EPI == 0) {
          if (col < scale_cols) v *= SCALEQ;
          Cb[off] = f2b(v);
        } else if (EPI == 1) {
          Cf[off] += v;
        } else if (EPI == 3) {
          Cf[off] = v;
        } else {
          float e = EXP2(v * (2.3022082f + 0.10294324f * v * v));
          Cb[off] = f2b(v * (1.0f - RCP(e + 1.0f)));
        }
      }
    }
  }
}

// ---------------- MFMA causal flash attention, uniform 8-tile chunks --------
// qb (128 q-rows) has ceil((2qb+2)/8) = qb/4+1 chunks of exactly 8 KV tiles
// (last may be shorter). Slots per bh = 144; grid (144, 16) = 2304 blocks.
// XCD-bijective swizzle keeps each bh's chunks on one XCD (K/V L2-resident).
__global__ __launch_bounds__(256) void attn_k(const u16* __restrict__ qkv,
                                              u16* __restrict__ Opart,
                                              float* __restrict__ ml) {
  __shared__ u16 Ks[2][64 * 64];
  __shared__ u16 Vt[2][64 * 64];
  int tid = threadIdx.x;
  int w = tid >> 6, l = tid & 63;
  int hh = l >> 5, c = l & 31;
  int flat = blockIdx.y * 144 + blockIdx.x;
  int swz = (flat & 7) * 288 + (flat >> 3);      // 2304/8 = 288
  int bh = swz / 144, slot = swz - bh * 144;
  int g = 0;
  while (2 * (g + 1) * (g + 2) <= slot) g++;     // group index 0..7
  int s2 = slot - 2 * g * (g + 1);
  int qb = 4 * g + s2 / (g + 1);
  int ck = s2 - (s2 / (g + 1)) * (g + 1);
  int ntot = 2 * qb + 2;
  int kt0 = ck * 8;
  int kt1 = kt0 + 8 < ntot ? kt0 + 8 : ntot;
  int b = bh >> 3, hd = bh & 7;
  int q0w = qb * 128 + w * 32;
  int q_abs = q0w + c;
  size_t base = (size_t)b * T_ * 1536;
  bf16x8 qf[4];
  const u16* qp = qkv + base + (size_t)q_abs * 1536 + hd * 64 + hh * 8;
#pragma unroll
  for (int kk = 0; kk < 4; kk++) qf[kk] = *(const bf16x8*)(qp + kk * 16);
  f32x16 oa0 = {}, oa1 = {};
  float m_run = -1e30f, l_run = 0.f;
  int sp = tid >> 3, d8 = (tid & 7) * 8;
  int r0 = sp * 2, r1 = r0 + 1;
  const u16* kvbase = qkv + base + DM + hd * 64 + d8;
  uint4 kreg0, kreg1, vreg0, vreg1;
#define AGLOAD(KT) { \
    const u16* s0_ = kvbase + (size_t)((KT) * 64 + r0) * 1536; \
    kreg0 = *(const uint4*)s0_; vreg0 = *(const uint4*)(s0_ + DM); \
    const u16* s1_ = s0_ + 1536; \
    kreg1 = *(const uint4*)s1_; vreg1 = *(const uint4*)(s1_ + DM); }
  AGLOAD(kt0);
  for (int kt = kt0; kt < kt1; kt++) {
    u16* Kb = Ks[kt & 1];
    u16* Vb = Vt[kt & 1];
    *(uint4*)&Kb[lsw(r0, d8)] = kreg0;
    *(uint4*)&Kb[lsw(r1, d8)] = kreg1;
    {
      const u16* v0 = (const u16*)&vreg0;
      const u16* v1 = (const u16*)&vreg1;
#pragma unroll
      for (int j = 0; j < 8; j++) {
        u32 pw = (u32)v0[j] | ((u32)v1[j] << 16);
        *(u32*)&Vb[lsw(d8 + j, r0)] = pw;
      }
    }
    if (kt + 1 < kt1) AGLOAD(kt + 1);
    __syncthreads();
    if (kt * 64 > q0w + 31) continue;  // fully masked for this wave
    bool needMask = (kt * 64 + 63 > q0w);
    f32x16 sa0 = {}, sa1 = {};
    __builtin_amdgcn_s_setprio(1);
#pragma unroll
    for (int kk = 0; kk < 4; kk++) {
      bf16x8 ka  = *(const bf16x8*)&Kb[lsw(c,      kk * 16 + hh * 8)];
      bf16x8 kb2 = *(const bf16x8*)&Kb[lsw(32 + c, kk * 16 + hh * 8)];
      sa0 = __builtin_amdgcn_mfma_f32_32x32x16_bf16(ka,  qf[kk], sa0, 0, 0, 0);
      sa1 = __builtin_amdgcn_mfma_f32_32x32x16_bf16(kb2, qf[kk], sa1, 0, 0, 0);
    }
    __builtin_amdgcn_s_setprio(0);
    if (needMask) {
#pragma unroll
      for (int gi = 0; gi < 4; gi++)
#pragma unroll
        for (int i = 0; i < 4; i++) {
          int krow = kt * 64 + gi * 8 + hh * 4 + i;
          if (krow > q_abs)      sa0[gi * 4 + i] = -1e30f;
          if (krow + 32 > q_abs) sa1[gi * 4 + i] = -1e30f;
        }
    }
    float pm = -1e30f;
#pragma unroll
    for (int r = 0; r < 16; r++) pm = fmaxf(pm, fmaxf(sa0[r], sa1[r]));
    pm = fmaxf(pm, __shfl_xor(pm, 32));
    if (!__all(pm - m_run <= 8.0f)) {
      float mnew = fmaxf(m_run, pm);
      float corr = EXP2(m_run - mnew);
      l_run *= corr;
#pragma unroll
      for (int r = 0; r < 16; r++) { oa0[r] *= corr; oa1[r] *= corr; }
      m_run = mnew;
    }
    float lsum = 0.f;
#pragma unroll
    for (int r = 0; r < 16; r++) {
      float e0 = EXP2(sa0[r] - m_run); sa0[r] = e0;
      float e1 = EXP2(sa1[r] - m_run); sa1[r] = e1;
      lsum += e0 + e1;
    }
    lsum += __shfl_xor(lsum, 32);
    l_run += lsum;
    u32 Aw[8], Bw_[8], Asw[8], Bsw[8];
#pragma unroll
    for (int r2 = 0; r2 < 4; r2++) {
      Aw[r2]      = cvtpk(sa0[4 * r2 + 0], sa0[4 * r2 + 1]);
      Bw_[r2]     = cvtpk(sa0[4 * r2 + 2], sa0[4 * r2 + 3]);
      Aw[4 + r2]  = cvtpk(sa1[4 * r2 + 0], sa1[4 * r2 + 1]);
      Bw_[4 + r2] = cvtpk(sa1[4 * r2 + 2], sa1[4 * r2 + 3]);
    }
#pragma unroll
    for (int i = 0; i < 8; i++) {
      Asw[i] = __shfl_xor(Aw[i], 32);
      Bsw[i] = __shfl_xor(Bw_[i], 32);
    }
    __builtin_amdgcn_s_setprio(1);
#pragma unroll
    for (int ks = 0; ks < 4; ks++) {
      int mo = (ks >> 1) * 4;
      int r2e = mo + 2 * (ks & 1), r2o = r2e + 1;
      union { u32 wd[4]; bf16x8 v; } u;
      u.wd[0] = hh ? Asw[r2o] : Aw[r2e];
      u.wd[1] = hh ? Bsw[r2o] : Bw_[r2e];
      u.wd[2] = hh ? Aw[r2o]  : Asw[r2e];
      u.wd[3] = hh ? Bw_[r2o] : Bsw[r2e];
      bf16x8 va = *(const bf16x8*)&Vb[lsw(c,      ks * 16 + hh * 8)];
      bf16x8 vb = *(const bf16x8*)&Vb[lsw(32 + c, ks * 16 + hh * 8)];
      oa0 = __builtin_amdgcn_mfma_f32_32x32x16_bf16(va, u.v, oa0, 0, 0, 0);
      oa1 = __builtin_amdgcn_mfma_f32_32x32x16_bf16(vb, u.v, oa1, 0, 0, 0);
    }
    __builtin_amdgcn_s_setprio(0);
  }
  // write unnormalized partial
  int sidx = bh * 144 + slot;
  u16* op = Opart + ((size_t)sidx * 128 + w * 32 + c) * 64;
#pragma unroll
  for (int gi = 0; gi < 4; gi++) {
    uint2 s0, s1;
    s0.x = cvtpk(oa0[4*gi+0], oa0[4*gi+1]);
    s0.y = cvtpk(oa0[4*gi+2], oa0[4*gi+3]);
    s1.x = cvtpk(oa1[4*gi+0], oa1[4*gi+1]);
    s1.y = cvtpk(oa1[4*gi+2], oa1[4*gi+3]);
    int d0 = gi * 8 + hh * 4;
    *(uint2*)(op + d0)      = s0;
    *(uint2*)(op + 32 + d0) = s1;
  }
  if (hh == 0) {
    float2 p; p.x = m_run; p.y = l_run;
    *(float2*)&ml[((size_t)sidx * 128 + w * 32 + c) * 2] = p;
  }
}

// ---------------- combine partials -> attno ----------------
__global__ __launch_bounds__(256) void comb_k(
    const u16* __restrict__ Opart, const float* __restrict__ ml,
    u16* __restrict__ attno) {
  int gi = blockIdx.x * 256 + threadIdx.x;     // 16*4096*64
  int d = gi & 63, bhq = gi >> 6;
  int bh = bhq >> 12, q = bhq & 4095;
  int qb = q >> 7, ri = q & 127;
  int g = qb >> 2;
  int nc = g + 1;
  int bs = 2 * g * (g + 1) + (qb & 3) * (g + 1);
  int s0 = bh * 144 + bs;
  float M = -1e30f;
  for (int cc = 0; cc < nc; cc++)
    M = fmaxf(M, ml[((size_t)(s0 + cc) * 128 + ri) * 2]);
  float O = 0.f, L = 0.f;
  for (int cc = 0; cc < nc; cc++) {
    float2 p = *(const float2*)&ml[((size_t)(s0 + cc) * 128 + ri) * 2];
    float wgt = EXP2(p.x - M);
    L += p.y * wgt;
    O += b2f(Opart[((size_t)(s0 + cc) * 128 + ri) * 64 + d]) * wgt;
  }
  int b = bh >> 3, hd = bh & 7;
  attno[((size_t)b * T_ + q) * DM + hd * 64 + d] = f2b(O / L);
}

// ---------------- head: out = lnf(bf16) @ head_w + head_b, N=64 ----------------
__global__ __launch_bounds__(256) void head_k(
    const u16* __restrict__ xb, const float* __restrict__ W,
    const float* __restrict__ bias, float* __restrict__ out) {
  int wid = threadIdx.x >> 6, lane = threadIdx.x & 63;
  int row = blockIdx.x * 4 + wid;
  const u16* xr = xb + (size_t)row * DM;
  float a0 = 0.f, a1 = 0.f, a2 = 0.f, a3 = 0.f;
  for (int d = 0; d < DM; d += 8) {
    uint4 xv = *(const uint4*)(xr + d);
    const u16* xp = (const u16*)&xv;
    const float* Wp = W + (size_t)d * 64 + lane;
    a0 += b2f(xp[0]) * Wp[0];
    a1 += b2f(xp[1]) * Wp[64];
    a2 += b2f(xp[2]) * Wp[128];
    a3 += b2f(xp[3]) * Wp[192];
    a0 += b2f(xp[4]) * Wp[256];
    a1 += b2f(xp[5]) * Wp[320];
    a2 += b2f(xp[6]) * Wp[384];
    a3 += b2f(xp[7]) * Wp[448];
  }
  out[(size_t)row * 64 + lane] = a0 + a1 + a2 + a3 + bias[lane];
}

extern "C" void kernel_launch(void* const* d_in, const int* in_sizes, int n_in,
                              void* d_out, int out_size, void* d_ws, size_t ws_size,
                              hipStream_t stream) {
  (void)in_sizes; (void)n_in; (void)out_size; (void)ws_size;
  const float* x_in  = (const float*)d_in[0];
  const float* inp_w = (const float*)d_in[1];
  const float* inp_b = (const float*)d_in[2];
  const float* pos   = (const float*)d_in[3];
  const float* ln1g  = (const float*)d_in[4];
  const float* ln1b  = (const float*)d_in[5];
  const float* qkvw  = (const float*)d_in[6];
  const float* projw = (const float*)d_in[7];
  const float* ln2g  = (const float*)d_in[8];
  const float* ln2b  = (const float*)d_in[9];
  const float* fc1w  = (const float*)d_in[10];
  const float* fc2w  = (const float*)d_in[11];
  const float* lnfg  = (const float*)d_in[12];
  const float* lnfb  = (const float*)d_in[13];
  const float* headw = (const float*)d_in[14];
  const float* headb = (const float*)d_in[15];

  char* ws = (char*)d_ws;
  size_t off = 0;
  float* x     = (float*)(ws + off); off += (size_t)MTOT * DM * 4;
  u16*  lnb    = (u16*)(ws + off);   off += (size_t)MTOT * DM * 2;
  u16*  qkvb   = (u16*)(ws + off);   off += (size_t)MTOT * 3 * DM * 2;
  u16*  attno  = (u16*)(ws + off);   off += (size_t)MTOT * DM * 2;
  u16*  ff     = qkvb;  // reuses qkv+attno regions
  u16*  qkvt   = (u16*)(ws + off);   off += (size_t)4 * DM * 3 * DM * 2;
  u16*  projt  = (u16*)(ws + off);   off += (size_t)4 * DM * DM * 2;
  u16*  fc1t   = (u16*)(ws + off);   off += (size_t)4 * DM * DFF * 2;
  u16*  fc2t   = (u16*)(ws + off);   off += (size_t)4 * DFF * DM * 2;
  // shared scratch: Opart+ml (attn..comb) aliases fc2 partials (fc2..next ln1)
  char* shared = ws + off;
  u16*  Opart  = (u16*)shared;                                    // 16*144*128*64*2 = 37.75 MB
  float* mlbuf = (float*)(shared + (size_t)16 * 144 * 128 * 64 * 2);  // 2.36 MB
  float* fcp   = (float*)shared;                                  // 2*8192*512*4 = 33.55 MB

  wconv_k<<<dim3(16, 48, 4), 256, 0, stream>>>(qkvw,  qkvt, DM, 3 * DM);
  wconv_k<<<dim3(16, 16, 4), 256, 0, stream>>>(projw, projt, DM, DM);
  wconv_k<<<dim3(16, 64, 4), 256, 0, stream>>>(fc1w,  fc1t, DM, DFF);
  wconv_k<<<dim3(64, 16, 4), 256, 0, stream>>>(fc2w,  fc2t, DFF, DM);

  embed_k<<<(MTOT * DM) / 256, 256, 0, stream>>>(x_in, inp_w, inp_b, pos, x);
  for (int ly = 0; ly < 4; ly++) {
    if (ly == 0)
      ln_k<0><<<MTOT / 4, 256, 0, stream>>>(x, nullptr, ln1g, ln1b, lnb);
    else
      ln_k<2><<<MTOT / 4, 256, 0, stream>>>(x, fcp, ln1g + ly * DM, ln1b + ly * DM, lnb);
    gemm_k<0><<<dim3(12, 64), 256, 0, stream>>>(lnb, qkvt + (size_t)ly * DM * 3 * DM,
                                                qkvb, nullptr, MTOT, 3 * DM, DM, DM, DM);
    attn_k<<<dim3(144, 16), 256, 0, stream>>>(qkvb, Opart, mlbuf);
    comb_k<<<(16 * 4096 * 64) / 256, 256, 0, stream>>>(Opart, mlbuf, attno);
    gemm_k<1><<<dim3(4, 64), 256, 0, stream>>>(attno, projt + (size_t)ly * DM * DM,
                                               nullptr, x, MTOT, DM, DM, DM, 0);
    ln_k<0><<<MTOT / 4, 256, 0, stream>>>(x, nullptr, ln2g + ly * DM, ln2b + ly * DM, lnb);
    gemm_k<2><<<dim3(16, 64), 256, 0, stream>>>(lnb, fc1t + (size_t)ly * DM * DFF,
                                                ff, nullptr, MTOT, DFF, DM, DM, 0);
    gemm_k<3><<<dim3(4, 64, 2), 256, 0, stream>>>(ff, fc2t + (size_t)ly * DFF * DM,
                                                  nullptr, fcp, MTOT, DM, DFF, DFF / 2, 0);
  }
  ln_k<2><<<MTOT / 4, 256, 0, stream>>>(x, fcp, lnfg, lnfb, lnb);
  head_k<<<MTOT / 4, 256, 0, stream>>>(lnb, headw, headb, (float*)d_out);
}